// Round 3
// baseline (281.802 us; speedup 1.0000x reference)
//
#include <hip/hip_runtime.h>

// MultiHeadAttention fused: B=2, T=2048, D=1024, H=16, DH=64.
// Inputs fp32 (per reference), output fp32. Internally bf16 MFMA, fp32 accum.
// Pipeline: [cvt x] + [transpose W] -> [QKV gemm (m97 staging, Q pre-scaled)]
//           -> [transpose V] -> [flash attn, static-max, KV-CHUNKED, NO-LDS-STAGING]
//           -> [combine partials] -> [out gemm 64x128 + bias]
//
// R12: KV-chunk split for causal balance (attn 62->51us, occupancy 10->14%).
// R14: drop K/V LDS staging entirely. K/V per bh = 256KB each, L2-resident
// (80 chunk-blocks share each bh) -> load MFMA fragments DIRECT from global
// (16B/lane, 64B/row segments). Removes both barriers per kv-tile (waves now
// fully independent), all ds_write staging, 18.4KB LDS. LDS = Ps only
// (9.2KB); occupancy cap moves to VGPR: __launch_bounds__(128,4) -> 16
// waves/CU. Guide Common-mistake #7 (m169): stage only what doesn't L2-fit.

typedef unsigned short u16;
typedef __attribute__((ext_vector_type(8))) short short8;   // 8 x bf16 (4 VGPRs)
typedef __attribute__((ext_vector_type(4))) short short4_t; // 4 x bf16 (8 B)
typedef __attribute__((ext_vector_type(4))) float f32x4;    // MFMA C/D frag

#define B_ 2
#define T_ 2048
#define D_ 1024
#define H_ 16
#define DH_ 64
#define M_ (B_ * T_)            // 4096 rows of x
#define SCALE_LOG2E 0.18033688011112042f  // (1/sqrt(64)) * log2(e) — folded into Q
#define NEG_BIG -3.0e4f         // mask sentinel: v_exp_f32(NEG_BIG) == 0

// partial-slot geometry: per (bh) 72 slots (qt 8..15: 2, 16..23: 3, 24..31: 4)
// slot payload: 64x64 fp32 O tile [q][dh] + 64 fp32 l  -> 4160 floats
#define SLOT_F 4160
#define SLOTS_PER_BH 72
#define OPART_BYTES ((size_t)32 * SLOTS_PER_BH * SLOT_F * 4)   // 38,338,560
#define WS_BASE_BYTES ((size_t)24 * 1024 * 1024 * 2)           // 48 MB (u16 pools)

// async global->LDS, 16B per lane; LDS dest = wave-uniform base + lane*16
#define GLOAD16(g, l)                                                     \
  __builtin_amdgcn_global_load_lds(                                       \
      (const __attribute__((address_space(1))) void*)(g),                 \
      (__attribute__((address_space(3))) void*)(l), 16, 0, 0)

__device__ __forceinline__ u16 f2bf(float f) {
  union { float f; unsigned u; } v; v.f = f;
  unsigned r = v.u + 0x7fffu + ((v.u >> 16) & 1u);  // RNE
  return (u16)(r >> 16);
}
__device__ __forceinline__ u16 f2bf_trunc(float f) {  // for P >= 0
  union { float f; unsigned u; } v; v.f = f;
  return (u16)(v.u >> 16);
}
__device__ __forceinline__ float exp2_raw(float x) {  // bare v_exp_f32
  float r;
  asm volatile("v_exp_f32 %0, %1" : "=v"(r) : "v"(x));
  return r;
}

// ---------------------------------------------------------------------------
// Kernel 0: convert x fp32 -> bf16. 4M elements, 8/thread.
// ---------------------------------------------------------------------------
__global__ __launch_bounds__(256) void cvt_x(const float* __restrict__ x,
                                             u16* __restrict__ xb) {
  const int i = (blockIdx.x * 256 + threadIdx.x) * 8;
  float4 a = *(const float4*)(x + i);
  float4 b = *(const float4*)(x + i + 4);
  short8 o;
  o[0] = (short)f2bf(a.x); o[1] = (short)f2bf(a.y);
  o[2] = (short)f2bf(a.z); o[3] = (short)f2bf(a.w);
  o[4] = (short)f2bf(b.x); o[5] = (short)f2bf(b.y);
  o[6] = (short)f2bf(b.z); o[7] = (short)f2bf(b.w);
  *(short8*)(xb + i) = o;
}

// ---------------------------------------------------------------------------
// Kernel 1: transpose + convert the 4 weight matrices fp32 [K][N] -> bf16 [N][K]
// grid (16,16,4), block 256. 64x64 tiles through LDS (+8 pad).
// ---------------------------------------------------------------------------
__global__ __launch_bounds__(256) void transpose_w(
    const float* __restrict__ w0, const float* __restrict__ w1,
    const float* __restrict__ w2, const float* __restrict__ w3,
    u16* __restrict__ outT) {
  __shared__ u16 Tl[64][72];
  const int z = blockIdx.z;
  const float* src = (z == 0) ? w0 : (z == 1) ? w1 : (z == 2) ? w2 : w3;
  const int r0 = blockIdx.y * 64, c0 = blockIdx.x * 64;
  const int tid = threadIdx.x;
  const int rr = tid >> 2, cc = (tid & 3) * 16;

  const float* p = src + (size_t)(r0 + rr) * D_ + c0 + cc;
  float4 f0 = *(const float4*)p;
  float4 f1 = *(const float4*)(p + 4);
  float4 f2 = *(const float4*)(p + 8);
  float4 f3 = *(const float4*)(p + 12);
  Tl[rr][cc + 0] = f2bf(f0.x); Tl[rr][cc + 1] = f2bf(f0.y);
  Tl[rr][cc + 2] = f2bf(f0.z); Tl[rr][cc + 3] = f2bf(f0.w);
  Tl[rr][cc + 4] = f2bf(f1.x); Tl[rr][cc + 5] = f2bf(f1.y);
  Tl[rr][cc + 6] = f2bf(f1.z); Tl[rr][cc + 7] = f2bf(f1.w);
  Tl[rr][cc + 8] = f2bf(f2.x); Tl[rr][cc + 9] = f2bf(f2.y);
  Tl[rr][cc +10] = f2bf(f2.z); Tl[rr][cc +11] = f2bf(f2.w);
  Tl[rr][cc +12] = f2bf(f3.x); Tl[rr][cc +13] = f2bf(f3.y);
  Tl[rr][cc +14] = f2bf(f3.z); Tl[rr][cc +15] = f2bf(f3.w);
  __syncthreads();

  u16* o = outT + (size_t)z * D_ * D_ + (size_t)(c0 + rr) * D_ + r0 + cc;
  short8 x0, x1;
#pragma unroll
  for (int i = 0; i < 8; i++) x0[i] = (short)Tl[cc + i][rr];
#pragma unroll
  for (int i = 0; i < 8; i++) x1[i] = (short)Tl[cc + 8 + i][rr];
  *(short8*)o = x0;
  *(short8*)(o + 8) = x1;
}

// ---------------------------------------------------------------------------
// Kernel 2: QKV projection. C[m][n] = sum_k x[m][k] * WT[n][k]. (bf16 in/out)
// m97-style staging. Q (z==0) is pre-scaled by SCALE_LOG2E.
// grid (8, 32, 3), block 256.
// ---------------------------------------------------------------------------
__global__ __launch_bounds__(256) void qkv_gemm(
    const u16* __restrict__ x, const u16* __restrict__ wT,
    u16* __restrict__ qkv) {
  __shared__ u16 As[128][32];  // unpadded: global_load_lds needs lane-order layout
  __shared__ u16 Bs[128][32];

  const int z = blockIdx.z;
  const u16* W = wT + (size_t)z * D_ * D_;
  u16* out = qkv + (size_t)z * M_ * D_;
  const int n0 = blockIdx.x * 128;
  const int m0 = blockIdx.y * 128;
  const int tid = threadIdx.x;
  const int lane = tid & 63, w = tid >> 6;
  const int quad = lane >> 4, l16 = lane & 15;
  const int wr = w >> 1, wc = w & 1;

  f32x4 acc[4][4] = {};
  const int grow = w * 16 + (lane >> 2);
  const int gcol = (lane & 3) * 8;
  u16* lA = (u16*)As + w * 512;   // 1024 B per wave
  u16* lB = (u16*)Bs + w * 512;

  for (int k0 = 0; k0 < D_; k0 += 32) {
    const u16* gA = x + (size_t)(m0 + grow) * D_ + k0 + gcol;
    const u16* gB = W + (size_t)(n0 + grow) * D_ + k0 + gcol;
    GLOAD16(gA, lA);
    GLOAD16(gA + (size_t)64 * D_, lA + 2048);
    GLOAD16(gB, lB);
    GLOAD16(gB + (size_t)64 * D_, lB + 2048);
    __syncthreads();

    short8 af[4], bf[4];
#pragma unroll
    for (int i = 0; i < 4; i++)
      af[i] = *(const short8*)&As[wr * 64 + i * 16 + l16][quad * 8];
#pragma unroll
    for (int i = 0; i < 4; i++)
      bf[i] = *(const short8*)&Bs[wc * 64 + i * 16 + l16][quad * 8];
#pragma unroll
    for (int i = 0; i < 4; i++)
#pragma unroll
      for (int j = 0; j < 4; j++)
        acc[i][j] = __builtin_amdgcn_mfma_f32_16x16x32_bf16(af[i], bf[j], acc[i][j], 0, 0, 0);
    __syncthreads();
  }

  const float osc = (z == 0) ? SCALE_LOG2E : 1.0f;  // pre-scale Q only
#pragma unroll
  for (int i = 0; i < 4; i++) {
#pragma unroll
    for (int j = 0; j < 4; j++) {
      const int n = n0 + wc * 64 + j * 16 + l16;
      const int h = n >> 6, dh = n & 63;
#pragma unroll
      for (int r = 0; r < 4; r++) {
        const int m = m0 + wr * 64 + i * 16 + quad * 4 + r;
        const int b = m >> 11, t = m & (T_ - 1);
        out[(((size_t)(b * H_ + h)) * T_ + t) * DH_ + dh] = f2bf(acc[i][j][r] * osc);
      }
    }
  }
}

// ---------------------------------------------------------------------------
// Kernel 2b: transpose V [bh][t][dh] -> V^T [bh][dh][t]. grid (32, 32), block 256.
// ---------------------------------------------------------------------------
__global__ __launch_bounds__(256) void transpose_v(
    const u16* __restrict__ v, u16* __restrict__ vT) {
  __shared__ u16 Tl[64][72];
  const int t0 = blockIdx.x * 64;
  const int bh = blockIdx.y;
  const int tid = threadIdx.x;
  const int rr = tid >> 2, cc = (tid & 3) * 16;

  const u16* p = v + (size_t)bh * T_ * DH_ + (size_t)(t0 + rr) * DH_ + cc;
  short8 a0 = *(const short8*)p;
  short8 a1 = *(const short8*)(p + 8);
  *(short8*)&Tl[rr][cc] = a0;
  *(short8*)&Tl[rr][cc + 8] = a1;
  __syncthreads();

  u16* o = vT + (size_t)bh * DH_ * T_ + (size_t)rr * T_ + t0 + cc;
  short8 x0, x1;
#pragma unroll
  for (int i = 0; i < 8; i++) x0[i] = (short)Tl[cc + i][rr];
#pragma unroll
  for (int i = 0; i < 8; i++) x1[i] = (short)Tl[cc + 8 + i][rr];
  *(short8*)o = x0;
  *(short8*)(o + 8) = x1;
}

// ---------------------------------------------------------------------------
// shared helper: slot base within a bh for split q-tile qt (qt in 8..31)
// ---------------------------------------------------------------------------
__device__ __forceinline__ int slot_base(int qt) {
  return (qt < 16) ? (qt - 8) * 2
       : (qt < 24) ? 16 + (qt - 16) * 3
                   : 40 + (qt - 24) * 4;
}

// ---------------------------------------------------------------------------
// Kernel 3: causal flash attention, static-max softmax, KV-CHUNKED,
// NO K/V LDS staging: fragments loaded direct from global (L2-resident).
// grid (80, 32), block 128 (2 independent waves x 32 q-rows). ZERO barriers.
// LDS = Ps only (9.2 KB). nc==1 -> direct bf16 ctx write; nc>1 -> fp32
// partial (O [q][dh] + l) plain stores, combined by kernel 3b.
// ---------------------------------------------------------------------------
__global__ __launch_bounds__(128, 4) void attn_chunk(
    const u16* __restrict__ qg, const u16* __restrict__ kg,
    const u16* __restrict__ vtg, u16* __restrict__ ctx,
    float* __restrict__ Opart) {
  __shared__ u16 Ps[2][2][16][72];  // [wave][qfrag][q][kv 0..63 + pad]

  const int cid = 79 - blockIdx.x;  // big chunks (high qt) dispatch first
  int qt, c, nc;
  if (cid < 8)       { qt = cid;                    c = 0;               nc = 1; }
  else if (cid < 24) { qt = 8  + ((cid - 8) >> 1);  c = (cid - 8) & 1;   nc = 2; }
  else if (cid < 48) { qt = 16 + (cid - 24) / 3;    c = (cid - 24) % 3;  nc = 3; }
  else               { qt = 24 + ((cid - 48) >> 2); c = (cid - 48) & 3;  nc = 4; }
  const int nt = qt + 1;
  const int kv_lo = (c * nt / nc) * 64;
  const int kv_hi = ((c + 1) * nt / nc) * 64;   // exclusive
  const int q0 = qt * 64;

  const int bh = blockIdx.y;
  const int tid = threadIdx.x;
  const int w = tid >> 6, lane = tid & 63;
  const int quad = lane >> 4, l16 = lane & 15;
  const size_t baseQK = (size_t)bh * T_ * DH_;
  const size_t baseV  = (size_t)bh * DH_ * T_;

  // wave w owns q rows [q0+32w, q0+32w+32) as two 16-row fragments
  const int qrowA = q0 + w * 32 + l16;
  const int qrowB = qrowA + 16;
  short8 qfA0 = *(const short8*)(qg + baseQK + (size_t)qrowA * DH_ + quad * 8);
  short8 qfA1 = *(const short8*)(qg + baseQK + (size_t)qrowA * DH_ + 32 + quad * 8);
  short8 qfB0 = *(const short8*)(qg + baseQK + (size_t)qrowB * DH_ + quad * 8);
  short8 qfB1 = *(const short8*)(qg + baseQK + (size_t)qrowB * DH_ + 32 + quad * 8);

  f32x4 oaccA[4] = {}, oaccB[4] = {};  // O^T: row dh = cb*16+quad*4+r, col q = l16
  float liA = 0.f, liB = 0.f;          // per-lane partial sum (16 kv slots/iter)

  // per-lane fragment bases for direct K/V loads (16B/lane, 64B/row segments)
  const u16* kRow = kg + baseQK + (size_t)l16 * DH_ + quad * 8;  // + (kv0+cb*16)*DH_
  const u16* vRow = vtg + baseV + (size_t)l16 * T_ + quad * 8;   // + cb*16*T_ + kv0

  for (int kv0 = kv_lo; kv0 < kv_hi; kv0 += 64) {
    // issue all K+V fragment loads up front; vf stays in flight through QK^T
    short8 kf0[4], kf1[4], vf0[4], vf1[4];
#pragma unroll
    for (int cb = 0; cb < 4; cb++) {
      const u16* kp = kRow + (size_t)(kv0 + cb * 16) * DH_;
      kf0[cb] = *(const short8*)kp;
      kf1[cb] = *(const short8*)(kp + 32);
    }
#pragma unroll
    for (int cb = 0; cb < 4; cb++) {
      const u16* vp = vRow + (size_t)(cb * 16) * T_ + kv0;
      vf0[cb] = *(const short8*)vp;
      vf1[cb] = *(const short8*)(vp + 32);
    }

    // S^T = K·Q^T for both fragments (Q pre-scaled by SCALE_LOG2E)
    f32x4 svA[4], svB[4];
    __builtin_amdgcn_s_setprio(1);
#pragma unroll
    for (int cb = 0; cb < 4; cb++) {
      f32x4 z = {};
      svA[cb] = __builtin_amdgcn_mfma_f32_16x16x32_bf16(kf0[cb], qfA0, z, 0, 0, 0);
      svA[cb] = __builtin_amdgcn_mfma_f32_16x16x32_bf16(kf1[cb], qfA1, svA[cb], 0, 0, 0);
      svB[cb] = __builtin_amdgcn_mfma_f32_16x16x32_bf16(kf0[cb], qfB0, z, 0, 0, 0);
      svB[cb] = __builtin_amdgcn_mfma_f32_16x16x32_bf16(kf1[cb], qfB1, svB[cb], 0, 0, 0);
    }
    __builtin_amdgcn_s_setprio(0);

    // p = exp2(s) (static max = 0); mask only the diagonal tile
    float pA[4][4], pB[4][4];
    if (kv0 == q0) {
#pragma unroll
      for (int cb = 0; cb < 4; cb++)
#pragma unroll
        for (int r = 0; r < 4; r++) {
          const int kv = kv0 + cb * 16 + quad * 4 + r;
          pA[cb][r] = exp2_raw((kv <= qrowA) ? svA[cb][r] : NEG_BIG);
          pB[cb][r] = exp2_raw((kv <= qrowB) ? svB[cb][r] : NEG_BIG);
        }
    } else {
#pragma unroll
      for (int cb = 0; cb < 4; cb++)
#pragma unroll
        for (int r = 0; r < 4; r++) {
          pA[cb][r] = exp2_raw(svA[cb][r]);
          pB[cb][r] = exp2_raw(svB[cb][r]);
        }
    }
#pragma unroll
    for (int cb = 0; cb < 4; cb++)
#pragma unroll
      for (int r = 0; r < 4; r++) { liA += pA[cb][r]; liB += pB[cb][r]; }

    // P round-trip (packed b64 writes; wave-private LDS is in-order) + PV
#pragma unroll
    for (int cb = 0; cb < 4; cb++) {
      short4_t pkA, pkB;
#pragma unroll
      for (int r = 0; r < 4; r++) {
        pkA[r] = (short)f2bf_trunc(pA[cb][r]);
        pkB[r] = (short)f2bf_trunc(pB[cb][r]);
      }
      *(short4_t*)&Ps[w][0][l16][cb * 16 + quad * 4] = pkA;
      *(short4_t*)&Ps[w][1][l16][cb * 16 + quad * 4] = pkB;
    }
    short8 paA0 = *(const short8*)&Ps[w][0][l16][quad * 8];
    short8 paA1 = *(const short8*)&Ps[w][0][l16][32 + quad * 8];
    short8 paB0 = *(const short8*)&Ps[w][1][l16][quad * 8];
    short8 paB1 = *(const short8*)&Ps[w][1][l16][32 + quad * 8];
    __builtin_amdgcn_s_setprio(1);
#pragma unroll
    for (int cb = 0; cb < 4; cb++) {
      oaccA[cb] = __builtin_amdgcn_mfma_f32_16x16x32_bf16(vf0[cb], paA0, oaccA[cb], 0, 0, 0);
      oaccA[cb] = __builtin_amdgcn_mfma_f32_16x16x32_bf16(vf1[cb], paA1, oaccA[cb], 0, 0, 0);
      oaccB[cb] = __builtin_amdgcn_mfma_f32_16x16x32_bf16(vf0[cb], paB0, oaccB[cb], 0, 0, 0);
      oaccB[cb] = __builtin_amdgcn_mfma_f32_16x16x32_bf16(vf1[cb], paB1, oaccB[cb], 0, 0, 0);
    }
    __builtin_amdgcn_s_setprio(0);
  }

  // reduce l across quads (all lanes end with the full row sum)
  liA += __shfl_xor(liA, 16, 64); liA += __shfl_xor(liA, 32, 64);
  liB += __shfl_xor(liB, 16, 64); liB += __shfl_xor(liB, 32, 64);

  if (nc == 1) {
    // sole chunk: normalize and write ctx bf16 directly
    const int b = bh >> 4, h = bh & 15;
    const float invA = 1.0f / liA, invB = 1.0f / liB;
    u16* outA = ctx + ((size_t)(b * T_ + qrowA)) * D_ + h * 64 + quad * 4;
    u16* outB = ctx + ((size_t)(b * T_ + qrowB)) * D_ + h * 64 + quad * 4;
#pragma unroll
    for (int cb = 0; cb < 4; cb++) {
      short4_t oA, oB;
#pragma unroll
      for (int r = 0; r < 4; r++) {
        oA[r] = (short)f2bf(oaccA[cb][r] * invA);
        oB[r] = (short)f2bf(oaccB[cb][r] * invB);
      }
      *(short4_t*)(outA + cb * 16) = oA;
      *(short4_t*)(outB + cb * 16) = oB;
    }
  } else {
    // partial store: O tile [q 64][dh 64] fp32 (+ l[64]) -> float4 per cb
    float* slot = Opart + ((size_t)bh * SLOTS_PER_BH + slot_base(qt) + c) * SLOT_F;
    float* pA = slot + (size_t)(w * 32 + l16) * 64 + quad * 4;
    float* pB = slot + (size_t)(w * 32 + 16 + l16) * 64 + quad * 4;
#pragma unroll
    for (int cb = 0; cb < 4; cb++) {
      *(f32x4*)(pA + cb * 16) = oaccA[cb];
      *(f32x4*)(pB + cb * 16) = oaccB[cb];
    }
    if (quad == 0) {
      slot[4096 + w * 32 + l16] = liA;
      slot[4096 + w * 32 + 16 + l16] = liB;
    }
  }
}

// ---------------------------------------------------------------------------
// Kernel 3b: combine partials for qt >= 8. grid (24, 32), block 256.
// Each block: one (bh, qt) 64x64 tile; sums nc<=4 slots, normalizes, bf16 out.
// ---------------------------------------------------------------------------
__global__ __launch_bounds__(256) void attn_combine(
    const float* __restrict__ Opart, u16* __restrict__ ctx) {
  __shared__ float ls[64];
  const int qt = blockIdx.x + 8;
  const int bh = blockIdx.y;
  const int nc = 1 + (qt >> 3);     // 2, 3 or 4
  const float* slot0 = Opart + ((size_t)bh * SLOTS_PER_BH + slot_base(qt)) * SLOT_F;
  const int tid = threadIdx.x;

  if (tid < 64) {
    float s = 0.f;
    for (int c = 0; c < nc; c++) s += slot0[(size_t)c * SLOT_F + 4096 + tid];
    ls[tid] = 1.0f / s;
  }
  __syncthreads();

  const int q = tid >> 2, d0 = (tid & 3) * 16;
  const float* p = slot0 + (size_t)q * 64 + d0;
  f32x4 a0 = *(const f32x4*)(p);
  f32x4 a1 = *(const f32x4*)(p + 4);
  f32x4 a2 = *(const f32x4*)(p + 8);
  f32x4 a3 = *(const f32x4*)(p + 12);
  for (int c = 1; c < nc; c++) {
    const float* pc = p + (size_t)c * SLOT_F;
    a0 += *(const f32x4*)(pc);
    a1 += *(const f32x4*)(pc + 4);
    a2 += *(const f32x4*)(pc + 8);
    a3 += *(const f32x4*)(pc + 12);
  }
  const float inv = ls[q];
  short8 o0, o1;
#pragma unroll
  for (int i = 0; i < 4; i++) {
    o0[i]     = (short)f2bf(a0[i] * inv);
    o0[i + 4] = (short)f2bf(a1[i] * inv);
    o1[i]     = (short)f2bf(a2[i] * inv);
    o1[i + 4] = (short)f2bf(a3[i] * inv);
  }
  const int b = bh >> 4, h = bh & 15;
  u16* op = ctx + ((size_t)(b * T_ + qt * 64 + q)) * D_ + h * 64 + d0;
  *(short8*)op = o0;
  *(short8*)(op + 8) = o1;
}

// ---------------------------------------------------------------------------
// Kernel 3-mono: fallback (previous measured-best attn) if ws too small.
// ---------------------------------------------------------------------------
__global__ __launch_bounds__(128) void attn_mono(
    const u16* __restrict__ qg, const u16* __restrict__ kg,
    const u16* __restrict__ vtg, u16* __restrict__ ctx) {
  __shared__ u16 Ks[64][72];
  __shared__ u16 Vs[64][72];
  __shared__ u16 Ps[2][2][16][72];

  const int qt = gridDim.x - 1 - blockIdx.x;
  const int bh = blockIdx.y;
  const int tid = threadIdx.x;
  const int w = tid >> 6, lane = tid & 63;
  const int quad = lane >> 4, l16 = lane & 15;
  const int q0 = qt * 64;
  const size_t baseQK = (size_t)bh * T_ * DH_;
  const size_t baseV  = (size_t)bh * DH_ * T_;

  const int qrowA = q0 + w * 32 + l16;
  const int qrowB = qrowA + 16;
  short8 qfA0 = *(const short8*)(qg + baseQK + (size_t)qrowA * DH_ + quad * 8);
  short8 qfA1 = *(const short8*)(qg + baseQK + (size_t)qrowA * DH_ + 32 + quad * 8);
  short8 qfB0 = *(const short8*)(qg + baseQK + (size_t)qrowB * DH_ + quad * 8);
  short8 qfB1 = *(const short8*)(qg + baseQK + (size_t)qrowB * DH_ + 32 + quad * 8);

  f32x4 oaccA[4] = {}, oaccB[4] = {};
  float liA = 0.f, liB = 0.f;

  const int srow = tid >> 1;
  const int scol = (tid & 1) * 32;

  const u16* kp = kg + baseQK + (size_t)srow * DH_ + scol;
  const u16* vp = vtg + baseV + (size_t)srow * T_ + scol;
  short8 kr0 = *(const short8*)kp;
  short8 kr1 = *(const short8*)(kp + 8);
  short8 kr2 = *(const short8*)(kp + 16);
  short8 kr3 = *(const short8*)(kp + 24);
  short8 vr0 = *(const short8*)vp;
  short8 vr1 = *(const short8*)(vp + 8);
  short8 vr2 = *(const short8*)(vp + 16);
  short8 vr3 = *(const short8*)(vp + 24);

  for (int kv0 = 0; kv0 <= q0; kv0 += 64) {
    __syncthreads();
    *(short8*)&Ks[srow][scol]      = kr0;
    *(short8*)&Ks[srow][scol + 8]  = kr1;
    *(short8*)&Ks[srow][scol + 16] = kr2;
    *(short8*)&Ks[srow][scol + 24] = kr3;
    *(short8*)&Vs[srow][scol]      = vr0;
    *(short8*)&Vs[srow][scol + 8]  = vr1;
    *(short8*)&Vs[srow][scol + 16] = vr2;
    *(short8*)&Vs[srow][scol + 24] = vr3;
    if (kv0 < q0) {
      const u16* kn = kg + baseQK + (size_t)(kv0 + 64 + srow) * DH_ + scol;
      const u16* vn = vtg + baseV + (size_t)srow * T_ + kv0 + 64 + scol;
      kr0 = *(const short8*)kn;
      kr1 = *(const short8*)(kn + 8);
      kr2 = *(const short8*)(kn + 16);
      kr3 = *(const short8*)(kn + 24);
      vr0 = *(const short8*)vn;
      vr1 = *(const short8*)(vn + 8);
      vr2 = *(const short8*)(vn + 16);
      vr3 = *(const short8*)(vn + 24);
    }
    __syncthreads();

    short8 kf0[4], kf1[4];
#pragma unroll
    for (int cb = 0; cb < 4; cb++) {
      kf0[cb] = *(const short8*)&Ks[cb * 16 + l16][quad * 8];
      kf1[cb] = *(const short8*)&Ks[cb * 16 + l16][32 + quad * 8];
    }

    f32x4 svA[4], svB[4];
#pragma unroll
    for (int cb = 0; cb < 4; cb++) {
      f32x4 z = {};
      svA[cb] = __builtin_amdgcn_mfma_f32_16x16x32_bf16(kf0[cb], qfA0, z, 0, 0, 0);
      svA[cb] = __builtin_amdgcn_mfma_f32_16x16x32_bf16(kf1[cb], qfA1, svA[cb], 0, 0, 0);
      svB[cb] = __builtin_amdgcn_mfma_f32_16x16x32_bf16(kf0[cb], qfB0, z, 0, 0, 0);
      svB[cb] = __builtin_amdgcn_mfma_f32_16x16x32_bf16(kf1[cb], qfB1, svB[cb], 0, 0, 0);
    }

    float pA[4][4], pB[4][4];
    if (kv0 == q0) {
#pragma unroll
      for (int cb = 0; cb < 4; cb++)
#pragma unroll
        for (int r = 0; r < 4; r++) {
          const int kv = kv0 + cb * 16 + quad * 4 + r;
          pA[cb][r] = exp2_raw((kv <= qrowA) ? svA[cb][r] : NEG_BIG);
          pB[cb][r] = exp2_raw((kv <= qrowB) ? svB[cb][r] : NEG_BIG);
        }
    } else {
#pragma unroll
      for (int cb = 0; cb < 4; cb++)
#pragma unroll
        for (int r = 0; r < 4; r++) {
          pA[cb][r] = exp2_raw(svA[cb][r]);
          pB[cb][r] = exp2_raw(svB[cb][r]);
        }
    }
#pragma unroll
    for (int cb = 0; cb < 4; cb++)
#pragma unroll
      for (int r = 0; r < 4; r++) { liA += pA[cb][r]; liB += pB[cb][r]; }

    short8 vf0[4], vf1[4];
#pragma unroll
    for (int cb = 0; cb < 4; cb++) {
      vf0[cb] = *(const short8*)&Vs[cb * 16 + l16][quad * 8];
      vf1[cb] = *(const short8*)&Vs[cb * 16 + l16][32 + quad * 8];
    }

#pragma unroll
    for (int cb = 0; cb < 4; cb++) {
      short4_t pkA, pkB;
#pragma unroll
      for (int r = 0; r < 4; r++) {
        pkA[r] = (short)f2bf_trunc(pA[cb][r]);
        pkB[r] = (short)f2bf_trunc(pB[cb][r]);
      }
      *(short4_t*)&Ps[w][0][l16][cb * 16 + quad * 4] = pkA;
      *(short4_t*)&Ps[w][1][l16][cb * 16 + quad * 4] = pkB;
    }
    short8 paA0 = *(const short8*)&Ps[w][0][l16][quad * 8];
    short8 paA1 = *(const short8*)&Ps[w][0][l16][32 + quad * 8];
    short8 paB0 = *(const short8*)&Ps[w][1][l16][quad * 8];
    short8 paB1 = *(const short8*)&Ps[w][1][l16][32 + quad * 8];
#pragma unroll
    for (int cb = 0; cb < 4; cb++) {
      oaccA[cb] = __builtin_amdgcn_mfma_f32_16x16x32_bf16(vf0[cb], paA0, oaccA[cb], 0, 0, 0);
      oaccA[cb] = __builtin_amdgcn_mfma_f32_16x16x32_bf16(vf1[cb], paA1, oaccA[cb], 0, 0, 0);
      oaccB[cb] = __builtin_amdgcn_mfma_f32_16x16x32_bf16(vf0[cb], paB0, oaccB[cb], 0, 0, 0);
      oaccB[cb] = __builtin_amdgcn_mfma_f32_16x16x32_bf16(vf1[cb], paB1, oaccB[cb], 0, 0, 0);
    }
  }

  liA += __shfl_xor(liA, 16, 64); liA += __shfl_xor(liA, 32, 64);
  liB += __shfl_xor(liB, 16, 64); liB += __shfl_xor(liB, 32, 64);
  const int b = bh >> 4, h = bh & 15;
  const float invA = 1.0f / liA, invB = 1.0f / liB;
  u16* outA = ctx + ((size_t)(b * T_ + qrowA)) * D_ + h * 64 + quad * 4;
  u16* outB = ctx + ((size_t)(b * T_ + qrowB)) * D_ + h * 64 + quad * 4;
#pragma unroll
  for (int cb = 0; cb < 4; cb++) {
    short4_t oA, oB;
#pragma unroll
    for (int r = 0; r < 4; r++) {
      oA[r] = (short)f2bf(oaccA[cb][r] * invA);
      oB[r] = (short)f2bf(oaccB[cb][r] * invB);
    }
    *(short4_t*)(outA + cb * 16) = oA;
    *(short4_t*)(outB + cb * 16) = oB;
  }
}

// ---------------------------------------------------------------------------
// Kernel 4: output projection + bias (m97 staging). out = ctx @ WoT^T + bo.
// 64x128 tile -> grid (8, 64) = 512 blocks = 2/CU (kept from R11: helped).
// block 256, 4 waves 2x2; each wave 32m x 64n (acc[2][4]). fp32 output.
// ---------------------------------------------------------------------------
__global__ __launch_bounds__(256) void out_gemm(
    const u16* __restrict__ ctx, const u16* __restrict__ woT,
    const float* __restrict__ bo, float* __restrict__ out) {
  __shared__ u16 As[64][32];
  __shared__ u16 Bs[128][32];

  const int n0 = blockIdx.x * 128;
  const int m0 = blockIdx.y * 64;
  const int tid = threadIdx.x;
  const int lane = tid & 63, w = tid >> 6;
  const int quad = lane >> 4, l16 = lane & 15;
  const int wr = w >> 1, wc = w & 1;

  f32x4 acc[2][4] = {};
  const int grow = w * 16 + (lane >> 2);
  const int gcol = (lane & 3) * 8;
  u16* lA = (u16*)As + w * 512;   // 1024 B per wave (A: 64 rows, 1 inst)
  u16* lB = (u16*)Bs + w * 512;

  for (int k0 = 0; k0 < D_; k0 += 32) {
    const u16* gA = ctx + (size_t)(m0 + grow) * D_ + k0 + gcol;
    const u16* gB = woT + (size_t)(n0 + grow) * D_ + k0 + gcol;
    GLOAD16(gA, lA);
    GLOAD16(gB, lB);
    GLOAD16(gB + (size_t)64 * D_, lB + 2048);
    __syncthreads();

    short8 af[2], bf[4];
#pragma unroll
    for (int i = 0; i < 2; i++)
      af[i] = *(const short8*)&As[wr * 32 + i * 16 + l16][quad * 8];
#pragma unroll
    for (int i = 0; i < 4; i++)
      bf[i] = *(const short8*)&Bs[wc * 64 + i * 16 + l16][quad * 8];
#pragma unroll
    for (int i = 0; i < 2; i++)
#pragma unroll
      for (int j = 0; j < 4; j++)
        acc[i][j] = __builtin_amdgcn_mfma_f32_16x16x32_bf16(af[i], bf[j], acc[i][j], 0, 0, 0);
    __syncthreads();
  }

#pragma unroll
  for (int i = 0; i < 2; i++) {
#pragma unroll
    for (int j = 0; j < 4; j++) {
      const int n = n0 + wc * 64 + j * 16 + l16;
      const float bias = bo[n];
#pragma unroll
      for (int r = 0; r < 4; r++) {
        const int m = m0 + wr * 32 + i * 16 + quad * 4 + r;
        out[(size_t)m * D_ + n] = acc[i][j][r] + bias;
      }
    }
  }
}

// ---------------------------------------------------------------------------
extern "C" void kernel_launch(void* const* d_in, const int* in_sizes, int n_in,
                              void* d_out, int out_size, void* d_ws, size_t ws_size,
                              hipStream_t stream) {
  const float* x  = (const float*)d_in[0];
  const float* Wq = (const float*)d_in[1];
  const float* Wk = (const float*)d_in[2];
  const float* Wv = (const float*)d_in[3];
  const float* Wo = (const float*)d_in[4];
  const float* bo = (const float*)d_in[5];
  float* out = (float*)d_out;

  // workspace carve (u16 elements): xb[4M] | wT[4M] | qkv[12M] | ctx[4M] = 48MB
  // then fp32 Opart partial buffer (38.3MB) for the chunked-attn path.
  // xb is dead after qkv_gemm -> reused as V^T buffer.
  u16* ws  = (u16*)d_ws;
  u16* xb  = ws;                                  // 4096*1024 (later: V^T)
  u16* wT  = xb + (size_t)M_ * D_;                // 4 * 1024*1024
  u16* qkv = wT + (size_t)4 * D_ * D_;            // 3 * 4096*1024
  u16* ctx = qkv + (size_t)3 * M_ * D_;           // 4096*1024
  u16* vT  = xb;
  float* Opart = (float*)(ctx + (size_t)M_ * D_); // at ws + 48MB

  cvt_x<<<dim3(M_ * D_ / (256 * 8)), 256, 0, stream>>>(x, xb);
  transpose_w<<<dim3(16, 16, 4), 256, 0, stream>>>(Wq, Wk, Wv, Wo, wT);
  qkv_gemm<<<dim3(D_ / 128, M_ / 128, 3), 256, 0, stream>>>(xb, wT, qkv);
  transpose_v<<<dim3(T_ / 64, B_ * H_), 256, 0, stream>>>(qkv + (size_t)2 * M_ * D_, vT);

  if (ws_size >= WS_BASE_BYTES + OPART_BYTES) {
    attn_chunk<<<dim3(80, B_ * H_), 128, 0, stream>>>(
        qkv, qkv + (size_t)M_ * D_, vT, ctx, Opart);
    attn_combine<<<dim3(24, B_ * H_), 256, 0, stream>>>(Opart, ctx);
  } else {
    attn_mono<<<dim3(T_ / 64, B_ * H_), 128, 0, stream>>>(
        qkv, qkv + (size_t)M_ * D_, vT, ctx);
  }

  out_gemm<<<dim3(D_ / 128, M_ / 64), 256, 0, stream>>>(ctx, wT + (size_t)3 * D_ * D_, bo, out);
}

// Round 4
// 198.561 us; speedup vs baseline: 1.4192x; 1.4192x over previous
//
#include <hip/hip_runtime.h>

// MultiHeadAttention fused: B=2, T=2048, D=1024, H=16, DH=64.
// Inputs fp32 (per reference), output fp32. Internally bf16 MFMA, fp32 accum.
// Pipeline: [cvt x] + [transpose W] -> [QKV gemm (m97 staging, Q pre-scaled)]
//           -> [transpose V] -> [flash attn, static-max, KV-CHUNKED, 4-wave]
//           -> [combine partials] -> [out gemm 64x128 + bias]
//
// R12: KV-chunk split for causal balance (attn 62->51us, occ 10->14%).
// R14 (REVERTED): direct-global K/V fragment loads thrashed L2 (working set
// per XCD >> 4MB): FETCH 64->197MB, WRITE 39->215MB, attn 51->138us. LDS
// staging is the reuse mechanism — keep it.
// R15: R12 structure, but 4-wave blocks on 128-row q-tiles. R12 occupancy was
// 14% = 1.15 waves/SIMD (LDS cap 5 blocks NOT reached) -> latency-bound.
// 256 threads share one Ks/Vs staging; LDS 36.9KB -> 4 blocks/CU = 16
// waves/CU; 40 chunks x 32 bh = 1280 blocks, <=8 kv-tiles each.

typedef unsigned short u16;
typedef __attribute__((ext_vector_type(8))) short short8;   // 8 x bf16 (4 VGPRs)
typedef __attribute__((ext_vector_type(4))) short short4_t; // 4 x bf16 (8 B)
typedef __attribute__((ext_vector_type(4))) float f32x4;    // MFMA C/D frag

#define B_ 2
#define T_ 2048
#define D_ 1024
#define H_ 16
#define DH_ 64
#define M_ (B_ * T_)            // 4096 rows of x
#define SCALE_LOG2E 0.18033688011112042f  // (1/sqrt(64)) * log2(e) — folded into Q
#define NEG_BIG -3.0e4f         // mask sentinel: v_exp_f32(NEG_BIG) == 0

// partial-slot geometry: per (bh) 36 slots (qt 4..7: 2, 8..11: 3, 12..15: 4)
// slot payload: 128x64 fp32 O tile [q][dh] + 128 fp32 l  -> 8320 floats
#define SLOT_F 8320
#define SLOTS_PER_BH 36
#define OPART_BYTES ((size_t)32 * SLOTS_PER_BH * SLOT_F * 4)   // 38,338,560
#define WS_BASE_BYTES ((size_t)24 * 1024 * 1024 * 2)           // 48 MB (u16 pools)

// async global->LDS, 16B per lane; LDS dest = wave-uniform base + lane*16
#define GLOAD16(g, l)                                                     \
  __builtin_amdgcn_global_load_lds(                                       \
      (const __attribute__((address_space(1))) void*)(g),                 \
      (__attribute__((address_space(3))) void*)(l), 16, 0, 0)

__device__ __forceinline__ u16 f2bf(float f) {
  union { float f; unsigned u; } v; v.f = f;
  unsigned r = v.u + 0x7fffu + ((v.u >> 16) & 1u);  // RNE
  return (u16)(r >> 16);
}
__device__ __forceinline__ u16 f2bf_trunc(float f) {  // for P >= 0
  union { float f; unsigned u; } v; v.f = f;
  return (u16)(v.u >> 16);
}
__device__ __forceinline__ float exp2_raw(float x) {  // bare v_exp_f32
  float r;
  asm volatile("v_exp_f32 %0, %1" : "=v"(r) : "v"(x));
  return r;
}

// ---------------------------------------------------------------------------
// Kernel 0: convert x fp32 -> bf16. 4M elements, 8/thread.
// ---------------------------------------------------------------------------
__global__ __launch_bounds__(256) void cvt_x(const float* __restrict__ x,
                                             u16* __restrict__ xb) {
  const int i = (blockIdx.x * 256 + threadIdx.x) * 8;
  float4 a = *(const float4*)(x + i);
  float4 b = *(const float4*)(x + i + 4);
  short8 o;
  o[0] = (short)f2bf(a.x); o[1] = (short)f2bf(a.y);
  o[2] = (short)f2bf(a.z); o[3] = (short)f2bf(a.w);
  o[4] = (short)f2bf(b.x); o[5] = (short)f2bf(b.y);
  o[6] = (short)f2bf(b.z); o[7] = (short)f2bf(b.w);
  *(short8*)(xb + i) = o;
}

// ---------------------------------------------------------------------------
// Kernel 1: transpose + convert the 4 weight matrices fp32 [K][N] -> bf16 [N][K]
// grid (16,16,4), block 256. 64x64 tiles through LDS (+8 pad).
// ---------------------------------------------------------------------------
__global__ __launch_bounds__(256) void transpose_w(
    const float* __restrict__ w0, const float* __restrict__ w1,
    const float* __restrict__ w2, const float* __restrict__ w3,
    u16* __restrict__ outT) {
  __shared__ u16 Tl[64][72];
  const int z = blockIdx.z;
  const float* src = (z == 0) ? w0 : (z == 1) ? w1 : (z == 2) ? w2 : w3;
  const int r0 = blockIdx.y * 64, c0 = blockIdx.x * 64;
  const int tid = threadIdx.x;
  const int rr = tid >> 2, cc = (tid & 3) * 16;

  const float* p = src + (size_t)(r0 + rr) * D_ + c0 + cc;
  float4 f0 = *(const float4*)p;
  float4 f1 = *(const float4*)(p + 4);
  float4 f2 = *(const float4*)(p + 8);
  float4 f3 = *(const float4*)(p + 12);
  Tl[rr][cc + 0] = f2bf(f0.x); Tl[rr][cc + 1] = f2bf(f0.y);
  Tl[rr][cc + 2] = f2bf(f0.z); Tl[rr][cc + 3] = f2bf(f0.w);
  Tl[rr][cc + 4] = f2bf(f1.x); Tl[rr][cc + 5] = f2bf(f1.y);
  Tl[rr][cc + 6] = f2bf(f1.z); Tl[rr][cc + 7] = f2bf(f1.w);
  Tl[rr][cc + 8] = f2bf(f2.x); Tl[rr][cc + 9] = f2bf(f2.y);
  Tl[rr][cc +10] = f2bf(f2.z); Tl[rr][cc +11] = f2bf(f2.w);
  Tl[rr][cc +12] = f2bf(f3.x); Tl[rr][cc +13] = f2bf(f3.y);
  Tl[rr][cc +14] = f2bf(f3.z); Tl[rr][cc +15] = f2bf(f3.w);
  __syncthreads();

  u16* o = outT + (size_t)z * D_ * D_ + (size_t)(c0 + rr) * D_ + r0 + cc;
  short8 x0, x1;
#pragma unroll
  for (int i = 0; i < 8; i++) x0[i] = (short)Tl[cc + i][rr];
#pragma unroll
  for (int i = 0; i < 8; i++) x1[i] = (short)Tl[cc + 8 + i][rr];
  *(short8*)o = x0;
  *(short8*)(o + 8) = x1;
}

// ---------------------------------------------------------------------------
// Kernel 2: QKV projection. C[m][n] = sum_k x[m][k] * WT[n][k]. (bf16 in/out)
// m97-style staging. Q (z==0) is pre-scaled by SCALE_LOG2E.
// grid (8, 32, 3), block 256.
// ---------------------------------------------------------------------------
__global__ __launch_bounds__(256) void qkv_gemm(
    const u16* __restrict__ x, const u16* __restrict__ wT,
    u16* __restrict__ qkv) {
  __shared__ u16 As[128][32];  // unpadded: global_load_lds needs lane-order layout
  __shared__ u16 Bs[128][32];

  const int z = blockIdx.z;
  const u16* W = wT + (size_t)z * D_ * D_;
  u16* out = qkv + (size_t)z * M_ * D_;
  const int n0 = blockIdx.x * 128;
  const int m0 = blockIdx.y * 128;
  const int tid = threadIdx.x;
  const int lane = tid & 63, w = tid >> 6;
  const int quad = lane >> 4, l16 = lane & 15;
  const int wr = w >> 1, wc = w & 1;

  f32x4 acc[4][4] = {};
  const int grow = w * 16 + (lane >> 2);
  const int gcol = (lane & 3) * 8;
  u16* lA = (u16*)As + w * 512;   // 1024 B per wave
  u16* lB = (u16*)Bs + w * 512;

  for (int k0 = 0; k0 < D_; k0 += 32) {
    const u16* gA = x + (size_t)(m0 + grow) * D_ + k0 + gcol;
    const u16* gB = W + (size_t)(n0 + grow) * D_ + k0 + gcol;
    GLOAD16(gA, lA);
    GLOAD16(gA + (size_t)64 * D_, lA + 2048);
    GLOAD16(gB, lB);
    GLOAD16(gB + (size_t)64 * D_, lB + 2048);
    __syncthreads();

    short8 af[4], bf[4];
#pragma unroll
    for (int i = 0; i < 4; i++)
      af[i] = *(const short8*)&As[wr * 64 + i * 16 + l16][quad * 8];
#pragma unroll
    for (int i = 0; i < 4; i++)
      bf[i] = *(const short8*)&Bs[wc * 64 + i * 16 + l16][quad * 8];
#pragma unroll
    for (int i = 0; i < 4; i++)
#pragma unroll
      for (int j = 0; j < 4; j++)
        acc[i][j] = __builtin_amdgcn_mfma_f32_16x16x32_bf16(af[i], bf[j], acc[i][j], 0, 0, 0);
    __syncthreads();
  }

  const float osc = (z == 0) ? SCALE_LOG2E : 1.0f;  // pre-scale Q only
#pragma unroll
  for (int i = 0; i < 4; i++) {
#pragma unroll
    for (int j = 0; j < 4; j++) {
      const int n = n0 + wc * 64 + j * 16 + l16;
      const int h = n >> 6, dh = n & 63;
#pragma unroll
      for (int r = 0; r < 4; r++) {
        const int m = m0 + wr * 64 + i * 16 + quad * 4 + r;
        const int b = m >> 11, t = m & (T_ - 1);
        out[(((size_t)(b * H_ + h)) * T_ + t) * DH_ + dh] = f2bf(acc[i][j][r] * osc);
      }
    }
  }
}

// ---------------------------------------------------------------------------
// Kernel 2b: transpose V [bh][t][dh] -> V^T [bh][dh][t]. grid (32, 32), block 256.
// ---------------------------------------------------------------------------
__global__ __launch_bounds__(256) void transpose_v(
    const u16* __restrict__ v, u16* __restrict__ vT) {
  __shared__ u16 Tl[64][72];
  const int t0 = blockIdx.x * 64;
  const int bh = blockIdx.y;
  const int tid = threadIdx.x;
  const int rr = tid >> 2, cc = (tid & 3) * 16;

  const u16* p = v + (size_t)bh * T_ * DH_ + (size_t)(t0 + rr) * DH_ + cc;
  short8 a0 = *(const short8*)p;
  short8 a1 = *(const short8*)(p + 8);
  *(short8*)&Tl[rr][cc] = a0;
  *(short8*)&Tl[rr][cc + 8] = a1;
  __syncthreads();

  u16* o = vT + (size_t)bh * DH_ * T_ + (size_t)rr * T_ + t0 + cc;
  short8 x0, x1;
#pragma unroll
  for (int i = 0; i < 8; i++) x0[i] = (short)Tl[cc + i][rr];
#pragma unroll
  for (int i = 0; i < 8; i++) x1[i] = (short)Tl[cc + 8 + i][rr];
  *(short8*)o = x0;
  *(short8*)(o + 8) = x1;
}

// ---------------------------------------------------------------------------
// shared helper: slot base within a bh for split q-tile qt (qt in 4..15)
// ---------------------------------------------------------------------------
__device__ __forceinline__ int slot_base(int qt) {
  return (qt < 8)  ? (qt - 4) * 2
       : (qt < 12) ? 8 + (qt - 8) * 3
                   : 20 + (qt - 12) * 4;
}

// ---------------------------------------------------------------------------
// Kernel 3: causal flash attention, static-max softmax, KV-CHUNKED, 4-WAVE.
// grid (40, 32), block 256 (4 waves x 32 q-rows = 128-row q-tile). Chunk cid
// covers q-tile qt (128 rows, nt = 2(qt+1) kv-tiles) with nc = 1+qt/4 chunks
// of <=8 kv tiles. nc==1 -> direct bf16 ctx write; nc>1 -> fp32 partial
// (O [q 128][dh 64] + l[128]) plain stores, combined by kernel 3b.
// LDS: Ks/Vs staged once per tile, shared by all 4 waves (reuse!).
// ---------------------------------------------------------------------------
__global__ __launch_bounds__(256) void attn_chunk(
    const u16* __restrict__ qg, const u16* __restrict__ kg,
    const u16* __restrict__ vtg, u16* __restrict__ ctx,
    float* __restrict__ Opart) {
  __shared__ u16 Ks[64][72];        // [kv][dh], +8 pad
  __shared__ u16 Vs[64][72];        // [dh][kv], +8 pad (from vT global)
  __shared__ u16 Ps[4][2][16][72];  // [wave][qfrag][q][kv 0..63 + pad]

  const int cid = 39 - blockIdx.x;  // big chunks (high qt) dispatch first
  int qt, c, nc;
  if (cid < 4)       { qt = cid;                    c = 0;               nc = 1; }
  else if (cid < 12) { qt = 4  + ((cid - 4) >> 1);  c = (cid - 4) & 1;   nc = 2; }
  else if (cid < 24) { qt = 8  + (cid - 12) / 3;    c = (cid - 12) % 3;  nc = 3; }
  else               { qt = 12 + ((cid - 24) >> 2); c = (cid - 24) & 3;  nc = 4; }
  const int nt = 2 * (qt + 1);                  // kv tiles for this q-tile
  const int kv_lo = (c * nt / nc) * 64;
  const int kv_hi = ((c + 1) * nt / nc) * 64;   // exclusive
  const int q0 = qt * 128;                      // first q row of tile

  const int bh = blockIdx.y;
  const int tid = threadIdx.x;
  const int w = tid >> 6, lane = tid & 63;
  const int quad = lane >> 4, l16 = lane & 15;
  const size_t baseQK = (size_t)bh * T_ * DH_;
  const size_t baseV  = (size_t)bh * DH_ * T_;

  // wave w owns q rows [q0+32w, q0+32w+32) as two 16-row fragments
  const int qw0 = q0 + w * 32;                  // wave's first row
  const int qrowA = qw0 + l16;
  const int qrowB = qrowA + 16;
  short8 qfA0 = *(const short8*)(qg + baseQK + (size_t)qrowA * DH_ + quad * 8);
  short8 qfA1 = *(const short8*)(qg + baseQK + (size_t)qrowA * DH_ + 32 + quad * 8);
  short8 qfB0 = *(const short8*)(qg + baseQK + (size_t)qrowB * DH_ + quad * 8);
  short8 qfB1 = *(const short8*)(qg + baseQK + (size_t)qrowB * DH_ + 32 + quad * 8);

  f32x4 oaccA[4] = {}, oaccB[4] = {};  // O^T: row dh = cb*16+quad*4+r, col q = l16
  float liA = 0.f, liB = 0.f;          // per-lane partial sum (16 kv slots/iter)

  const int srow = tid >> 2;          // 0..63 (4 threads per row)
  const int scol = (tid & 3) * 16;    // u16 offset: 0/16/32/48 (32 B per thread)

  // prefetch first tile of this chunk into registers (2x short8 per matrix)
  const u16* kp = kg + baseQK + (size_t)(kv_lo + srow) * DH_ + scol;
  const u16* vp = vtg + baseV + (size_t)srow * T_ + kv_lo + scol;
  short8 kr0 = *(const short8*)kp;
  short8 kr1 = *(const short8*)(kp + 8);
  short8 vr0 = *(const short8*)vp;
  short8 vr1 = *(const short8*)(vp + 8);

  for (int kv0 = kv_lo; kv0 < kv_hi; kv0 += 64) {
    __syncthreads();                 // LDS free (prev compute done)
    *(short8*)&Ks[srow][scol]     = kr0;
    *(short8*)&Ks[srow][scol + 8] = kr1;
    *(short8*)&Vs[srow][scol]     = vr0;
    *(short8*)&Vs[srow][scol + 8] = vr1;
    if (kv0 + 64 < kv_hi) {          // next tile's loads fly under compute
      const u16* kn = kg + baseQK + (size_t)(kv0 + 64 + srow) * DH_ + scol;
      const u16* vn = vtg + baseV + (size_t)srow * T_ + kv0 + 64 + scol;
      kr0 = *(const short8*)kn;
      kr1 = *(const short8*)(kn + 8);
      vr0 = *(const short8*)vn;
      vr1 = *(const short8*)(vn + 8);
    }
    __syncthreads();                 // LDS ready

    // K fragments read ONCE, shared by both q-fragments
    short8 kf0[4], kf1[4];
#pragma unroll
    for (int cb = 0; cb < 4; cb++) {
      kf0[cb] = *(const short8*)&Ks[cb * 16 + l16][quad * 8];
      kf1[cb] = *(const short8*)&Ks[cb * 16 + l16][32 + quad * 8];
    }

    // S^T = K·Q^T for both fragments (Q pre-scaled by SCALE_LOG2E)
    f32x4 svA[4], svB[4];
    __builtin_amdgcn_s_setprio(1);
#pragma unroll
    for (int cb = 0; cb < 4; cb++) {
      f32x4 z = {};
      svA[cb] = __builtin_amdgcn_mfma_f32_16x16x32_bf16(kf0[cb], qfA0, z, 0, 0, 0);
      svA[cb] = __builtin_amdgcn_mfma_f32_16x16x32_bf16(kf1[cb], qfA1, svA[cb], 0, 0, 0);
      svB[cb] = __builtin_amdgcn_mfma_f32_16x16x32_bf16(kf0[cb], qfB0, z, 0, 0, 0);
      svB[cb] = __builtin_amdgcn_mfma_f32_16x16x32_bf16(kf1[cb], qfB1, svB[cb], 0, 0, 0);
    }
    __builtin_amdgcn_s_setprio(0);

    // p = exp2(s) (static max = 0); mask when this wave's rows can be < kv.
    // (wave-uniform branch; both paths converge before next barrier)
    float pA[4][4], pB[4][4];
    if (kv0 + 63 > qw0) {
#pragma unroll
      for (int cb = 0; cb < 4; cb++)
#pragma unroll
        for (int r = 0; r < 4; r++) {
          const int kv = kv0 + cb * 16 + quad * 4 + r;
          pA[cb][r] = exp2_raw((kv <= qrowA) ? svA[cb][r] : NEG_BIG);
          pB[cb][r] = exp2_raw((kv <= qrowB) ? svB[cb][r] : NEG_BIG);
        }
    } else {
#pragma unroll
      for (int cb = 0; cb < 4; cb++)
#pragma unroll
        for (int r = 0; r < 4; r++) {
          pA[cb][r] = exp2_raw(svA[cb][r]);
          pB[cb][r] = exp2_raw(svB[cb][r]);
        }
    }
#pragma unroll
    for (int cb = 0; cb < 4; cb++)
#pragma unroll
      for (int r = 0; r < 4; r++) { liA += pA[cb][r]; liB += pB[cb][r]; }

    // V fragments read ONCE, shared by both q-fragments
    short8 vf0[4], vf1[4];
#pragma unroll
    for (int cb = 0; cb < 4; cb++) {
      vf0[cb] = *(const short8*)&Vs[cb * 16 + l16][quad * 8];
      vf1[cb] = *(const short8*)&Vs[cb * 16 + l16][32 + quad * 8];
    }

    // P round-trip (packed b64 writes; wave-private LDS is in-order) + PV
#pragma unroll
    for (int cb = 0; cb < 4; cb++) {
      short4_t pkA, pkB;
#pragma unroll
      for (int r = 0; r < 4; r++) {
        pkA[r] = (short)f2bf_trunc(pA[cb][r]);
        pkB[r] = (short)f2bf_trunc(pB[cb][r]);
      }
      *(short4_t*)&Ps[w][0][l16][cb * 16 + quad * 4] = pkA;
      *(short4_t*)&Ps[w][1][l16][cb * 16 + quad * 4] = pkB;
    }
    short8 paA0 = *(const short8*)&Ps[w][0][l16][quad * 8];
    short8 paA1 = *(const short8*)&Ps[w][0][l16][32 + quad * 8];
    short8 paB0 = *(const short8*)&Ps[w][1][l16][quad * 8];
    short8 paB1 = *(const short8*)&Ps[w][1][l16][32 + quad * 8];
    __builtin_amdgcn_s_setprio(1);
#pragma unroll
    for (int cb = 0; cb < 4; cb++) {
      oaccA[cb] = __builtin_amdgcn_mfma_f32_16x16x32_bf16(vf0[cb], paA0, oaccA[cb], 0, 0, 0);
      oaccA[cb] = __builtin_amdgcn_mfma_f32_16x16x32_bf16(vf1[cb], paA1, oaccA[cb], 0, 0, 0);
      oaccB[cb] = __builtin_amdgcn_mfma_f32_16x16x32_bf16(vf0[cb], paB0, oaccB[cb], 0, 0, 0);
      oaccB[cb] = __builtin_amdgcn_mfma_f32_16x16x32_bf16(vf1[cb], paB1, oaccB[cb], 0, 0, 0);
    }
    __builtin_amdgcn_s_setprio(0);
  }

  // reduce l across quads (all lanes end with the full row sum)
  liA += __shfl_xor(liA, 16, 64); liA += __shfl_xor(liA, 32, 64);
  liB += __shfl_xor(liB, 16, 64); liB += __shfl_xor(liB, 32, 64);

  if (nc == 1) {
    // sole chunk: normalize and write ctx bf16 directly
    const int b = bh >> 4, h = bh & 15;
    const float invA = 1.0f / liA, invB = 1.0f / liB;
    u16* outA = ctx + ((size_t)(b * T_ + qrowA)) * D_ + h * 64 + quad * 4;
    u16* outB = ctx + ((size_t)(b * T_ + qrowB)) * D_ + h * 64 + quad * 4;
#pragma unroll
    for (int cb = 0; cb < 4; cb++) {
      short4_t oA, oB;
#pragma unroll
      for (int r = 0; r < 4; r++) {
        oA[r] = (short)f2bf(oaccA[cb][r] * invA);
        oB[r] = (short)f2bf(oaccB[cb][r] * invB);
      }
      *(short4_t*)(outA + cb * 16) = oA;
      *(short4_t*)(outB + cb * 16) = oB;
    }
  } else {
    // partial store: O tile [q 128][dh 64] fp32 (+ l[128]) -> float4 per cb
    float* slot = Opart + ((size_t)bh * SLOTS_PER_BH + slot_base(qt) + c) * SLOT_F;
    float* pA = slot + (size_t)(w * 32 + l16) * 64 + quad * 4;
    float* pB = slot + (size_t)(w * 32 + 16 + l16) * 64 + quad * 4;
#pragma unroll
    for (int cb = 0; cb < 4; cb++) {
      *(f32x4*)(pA + cb * 16) = oaccA[cb];
      *(f32x4*)(pB + cb * 16) = oaccB[cb];
    }
    if (quad == 0) {
      slot[8192 + w * 32 + l16] = liA;
      slot[8192 + w * 32 + 16 + l16] = liB;
    }
  }
}

// ---------------------------------------------------------------------------
// Kernel 3b: combine partials for qt >= 4. grid (12, 32), block 256.
// Each block: one (bh, qt) 128x64 tile; sums nc<=4 slots, normalizes, bf16 out.
// ---------------------------------------------------------------------------
__global__ __launch_bounds__(256) void attn_combine(
    const float* __restrict__ Opart, u16* __restrict__ ctx) {
  __shared__ float ls[128];
  const int qt = blockIdx.x + 4;
  const int bh = blockIdx.y;
  const int nc = 1 + (qt >> 2);     // 2, 3 or 4
  const float* slot0 = Opart + ((size_t)bh * SLOTS_PER_BH + slot_base(qt)) * SLOT_F;
  const int tid = threadIdx.x;

  if (tid < 128) {
    float s = 0.f;
    for (int c = 0; c < nc; c++) s += slot0[(size_t)c * SLOT_F + 8192 + tid];
    ls[tid] = 1.0f / s;
  }
  __syncthreads();

  const int q = tid >> 1, d0 = (tid & 1) * 32;
  const float* p = slot0 + (size_t)q * 64 + d0;
  f32x4 a0 = *(const f32x4*)(p);
  f32x4 a1 = *(const f32x4*)(p + 4);
  f32x4 a2 = *(const f32x4*)(p + 8);
  f32x4 a3 = *(const f32x4*)(p + 12);
  f32x4 a4 = *(const f32x4*)(p + 16);
  f32x4 a5 = *(const f32x4*)(p + 20);
  f32x4 a6 = *(const f32x4*)(p + 24);
  f32x4 a7 = *(const f32x4*)(p + 28);
  for (int c = 1; c < nc; c++) {
    const float* pc = p + (size_t)c * SLOT_F;
    a0 += *(const f32x4*)(pc);
    a1 += *(const f32x4*)(pc + 4);
    a2 += *(const f32x4*)(pc + 8);
    a3 += *(const f32x4*)(pc + 12);
    a4 += *(const f32x4*)(pc + 16);
    a5 += *(const f32x4*)(pc + 20);
    a6 += *(const f32x4*)(pc + 24);
    a7 += *(const f32x4*)(pc + 28);
  }
  const float inv = ls[q];
  short8 o0, o1, o2, o3;
#pragma unroll
  for (int i = 0; i < 4; i++) {
    o0[i]     = (short)f2bf(a0[i] * inv);
    o0[i + 4] = (short)f2bf(a1[i] * inv);
    o1[i]     = (short)f2bf(a2[i] * inv);
    o1[i + 4] = (short)f2bf(a3[i] * inv);
    o2[i]     = (short)f2bf(a4[i] * inv);
    o2[i + 4] = (short)f2bf(a5[i] * inv);
    o3[i]     = (short)f2bf(a6[i] * inv);
    o3[i + 4] = (short)f2bf(a7[i] * inv);
  }
  const int b = bh >> 4, h = bh & 15;
  u16* op = ctx + ((size_t)(b * T_ + qt * 128 + q)) * D_ + h * 64 + d0;
  *(short8*)op = o0;
  *(short8*)(op + 8) = o1;
  *(short8*)(op + 16) = o2;
  *(short8*)(op + 24) = o3;
}

// ---------------------------------------------------------------------------
// Kernel 3-mono: fallback (previous measured-best attn) if ws too small.
// ---------------------------------------------------------------------------
__global__ __launch_bounds__(128) void attn_mono(
    const u16* __restrict__ qg, const u16* __restrict__ kg,
    const u16* __restrict__ vtg, u16* __restrict__ ctx) {
  __shared__ u16 Ks[64][72];
  __shared__ u16 Vs[64][72];
  __shared__ u16 Ps[2][2][16][72];

  const int qt = gridDim.x - 1 - blockIdx.x;
  const int bh = blockIdx.y;
  const int tid = threadIdx.x;
  const int w = tid >> 6, lane = tid & 63;
  const int quad = lane >> 4, l16 = lane & 15;
  const int q0 = qt * 64;
  const size_t baseQK = (size_t)bh * T_ * DH_;
  const size_t baseV  = (size_t)bh * DH_ * T_;

  const int qrowA = q0 + w * 32 + l16;
  const int qrowB = qrowA + 16;
  short8 qfA0 = *(const short8*)(qg + baseQK + (size_t)qrowA * DH_ + quad * 8);
  short8 qfA1 = *(const short8*)(qg + baseQK + (size_t)qrowA * DH_ + 32 + quad * 8);
  short8 qfB0 = *(const short8*)(qg + baseQK + (size_t)qrowB * DH_ + quad * 8);
  short8 qfB1 = *(const short8*)(qg + baseQK + (size_t)qrowB * DH_ + 32 + quad * 8);

  f32x4 oaccA[4] = {}, oaccB[4] = {};
  float liA = 0.f, liB = 0.f;

  const int srow = tid >> 1;
  const int scol = (tid & 1) * 32;

  const u16* kp = kg + baseQK + (size_t)srow * DH_ + scol;
  const u16* vp = vtg + baseV + (size_t)srow * T_ + scol;
  short8 kr0 = *(const short8*)kp;
  short8 kr1 = *(const short8*)(kp + 8);
  short8 kr2 = *(const short8*)(kp + 16);
  short8 kr3 = *(const short8*)(kp + 24);
  short8 vr0 = *(const short8*)vp;
  short8 vr1 = *(const short8*)(vp + 8);
  short8 vr2 = *(const short8*)(vp + 16);
  short8 vr3 = *(const short8*)(vp + 24);

  for (int kv0 = 0; kv0 <= q0; kv0 += 64) {
    __syncthreads();
    *(short8*)&Ks[srow][scol]      = kr0;
    *(short8*)&Ks[srow][scol + 8]  = kr1;
    *(short8*)&Ks[srow][scol + 16] = kr2;
    *(short8*)&Ks[srow][scol + 24] = kr3;
    *(short8*)&Vs[srow][scol]      = vr0;
    *(short8*)&Vs[srow][scol + 8]  = vr1;
    *(short8*)&Vs[srow][scol + 16] = vr2;
    *(short8*)&Vs[srow][scol + 24] = vr3;
    if (kv0 < q0) {
      const u16* kn = kg + baseQK + (size_t)(kv0 + 64 + srow) * DH_ + scol;
      const u16* vn = vtg + baseV + (size_t)srow * T_ + kv0 + 64 + scol;
      kr0 = *(const short8*)kn;
      kr1 = *(const short8*)(kn + 8);
      kr2 = *(const short8*)(kn + 16);
      kr3 = *(const short8*)(kn + 24);
      vr0 = *(const short8*)vn;
      vr1 = *(const short8*)(vn + 8);
      vr2 = *(const short8*)(vn + 16);
      vr3 = *(const short8*)(vn + 24);
    }
    __syncthreads();

    short8 kf0[4], kf1[4];
#pragma unroll
    for (int cb = 0; cb < 4; cb++) {
      kf0[cb] = *(const short8*)&Ks[cb * 16 + l16][quad * 8];
      kf1[cb] = *(const short8*)&Ks[cb * 16 + l16][32 + quad * 8];
    }

    f32x4 svA[4], svB[4];
#pragma unroll
    for (int cb = 0; cb < 4; cb++) {
      f32x4 z = {};
      svA[cb] = __builtin_amdgcn_mfma_f32_16x16x32_bf16(kf0[cb], qfA0, z, 0, 0, 0);
      svA[cb] = __builtin_amdgcn_mfma_f32_16x16x32_bf16(kf1[cb], qfA1, svA[cb], 0, 0, 0);
      svB[cb] = __builtin_amdgcn_mfma_f32_16x16x32_bf16(kf0[cb], qfB0, z, 0, 0, 0);
      svB[cb] = __builtin_amdgcn_mfma_f32_16x16x32_bf16(kf1[cb], qfB1, svB[cb], 0, 0, 0);
    }

    float pA[4][4], pB[4][4];
    if (kv0 == q0) {
#pragma unroll
      for (int cb = 0; cb < 4; cb++)
#pragma unroll
        for (int r = 0; r < 4; r++) {
          const int kv = kv0 + cb * 16 + quad * 4 + r;
          pA[cb][r] = exp2_raw((kv <= qrowA) ? svA[cb][r] : NEG_BIG);
          pB[cb][r] = exp2_raw((kv <= qrowB) ? svB[cb][r] : NEG_BIG);
        }
    } else {
#pragma unroll
      for (int cb = 0; cb < 4; cb++)
#pragma unroll
        for (int r = 0; r < 4; r++) {
          pA[cb][r] = exp2_raw(svA[cb][r]);
          pB[cb][r] = exp2_raw(svB[cb][r]);
        }
    }
#pragma unroll
    for (int cb = 0; cb < 4; cb++)
#pragma unroll
      for (int r = 0; r < 4; r++) { liA += pA[cb][r]; liB += pB[cb][r]; }

    short8 vf0[4], vf1[4];
#pragma unroll
    for (int cb = 0; cb < 4; cb++) {
      vf0[cb] = *(const short8*)&Vs[cb * 16 + l16][quad * 8];
      vf1[cb] = *(const short8*)&Vs[cb * 16 + l16][32 + quad * 8];
    }

#pragma unroll
    for (int cb = 0; cb < 4; cb++) {
      short4_t pkA, pkB;
#pragma unroll
      for (int r = 0; r < 4; r++) {
        pkA[r] = (short)f2bf_trunc(pA[cb][r]);
        pkB[r] = (short)f2bf_trunc(pB[cb][r]);
      }
      *(short4_t*)&Ps[w][0][l16][cb * 16 + quad * 4] = pkA;
      *(short4_t*)&Ps[w][1][l16][cb * 16 + quad * 4] = pkB;
    }
    short8 paA0 = *(const short8*)&Ps[w][0][l16][quad * 8];
    short8 paA1 = *(const short8*)&Ps[w][0][l16][32 + quad * 8];
    short8 paB0 = *(const short8*)&Ps[w][1][l16][quad * 8];
    short8 paB1 = *(const short8*)&Ps[w][1][l16][32 + quad * 8];
#pragma unroll
    for (int cb = 0; cb < 4; cb++) {
      oaccA[cb] = __builtin_amdgcn_mfma_f32_16x16x32_bf16(vf0[cb], paA0, oaccA[cb], 0, 0, 0);
      oaccA[cb] = __builtin_amdgcn_mfma_f32_16x16x32_bf16(vf1[cb], paA1, oaccA[cb], 0, 0, 0);
      oaccB[cb] = __builtin_amdgcn_mfma_f32_16x16x32_bf16(vf0[cb], paB0, oaccB[cb], 0, 0, 0);
      oaccB[cb] = __builtin_amdgcn_mfma_f32_16x16x32_bf16(vf1[cb], paB1, oaccB[cb], 0, 0, 0);
    }
  }

  liA += __shfl_xor(liA, 16, 64); liA += __shfl_xor(liA, 32, 64);
  liB += __shfl_xor(liB, 16, 64); liB += __shfl_xor(liB, 32, 64);
  const int b = bh >> 4, h = bh & 15;
  const float invA = 1.0f / liA, invB = 1.0f / liB;
  u16* outA = ctx + ((size_t)(b * T_ + qrowA)) * D_ + h * 64 + quad * 4;
  u16* outB = ctx + ((size_t)(b * T_ + qrowB)) * D_ + h * 64 + quad * 4;
#pragma unroll
  for (int cb = 0; cb < 4; cb++) {
    short4_t oA, oB;
#pragma unroll
    for (int r = 0; r < 4; r++) {
      oA[r] = (short)f2bf(oaccA[cb][r] * invA);
      oB[r] = (short)f2bf(oaccB[cb][r] * invB);
    }
    *(short4_t*)(outA + cb * 16) = oA;
    *(short4_t*)(outB + cb * 16) = oB;
  }
}

// ---------------------------------------------------------------------------
// Kernel 4: output projection + bias (m97 staging). out = ctx @ WoT^T + bo.
// 64x128 tile -> grid (8, 64) = 512 blocks = 2/CU (kept from R11: helped).
// block 256, 4 waves 2x2; each wave 32m x 64n (acc[2][4]). fp32 output.
// ---------------------------------------------------------------------------
__global__ __launch_bounds__(256) void out_gemm(
    const u16* __restrict__ ctx, const u16* __restrict__ woT,
    const float* __restrict__ bo, float* __restrict__ out) {
  __shared__ u16 As[64][32];
  __shared__ u16 Bs[128][32];

  const int n0 = blockIdx.x * 128;
  const int m0 = blockIdx.y * 64;
  const int tid = threadIdx.x;
  const int lane = tid & 63, w = tid >> 6;
  const int quad = lane >> 4, l16 = lane & 15;
  const int wr = w >> 1, wc = w & 1;

  f32x4 acc[2][4] = {};
  const int grow = w * 16 + (lane >> 2);
  const int gcol = (lane & 3) * 8;
  u16* lA = (u16*)As + w * 512;   // 1024 B per wave (A: 64 rows, 1 inst)
  u16* lB = (u16*)Bs + w * 512;

  for (int k0 = 0; k0 < D_; k0 += 32) {
    const u16* gA = ctx + (size_t)(m0 + grow) * D_ + k0 + gcol;
    const u16* gB = woT + (size_t)(n0 + grow) * D_ + k0 + gcol;
    GLOAD16(gA, lA);
    GLOAD16(gB, lB);
    GLOAD16(gB + (size_t)64 * D_, lB + 2048);
    __syncthreads();

    short8 af[2], bf[4];
#pragma unroll
    for (int i = 0; i < 2; i++)
      af[i] = *(const short8*)&As[wr * 32 + i * 16 + l16][quad * 8];
#pragma unroll
    for (int i = 0; i < 4; i++)
      bf[i] = *(const short8*)&Bs[wc * 64 + i * 16 + l16][quad * 8];
#pragma unroll
    for (int i = 0; i < 2; i++)
#pragma unroll
      for (int j = 0; j < 4; j++)
        acc[i][j] = __builtin_amdgcn_mfma_f32_16x16x32_bf16(af[i], bf[j], acc[i][j], 0, 0, 0);
    __syncthreads();
  }

#pragma unroll
  for (int i = 0; i < 2; i++) {
#pragma unroll
    for (int j = 0; j < 4; j++) {
      const int n = n0 + wc * 64 + j * 16 + l16;
      const float bias = bo[n];
#pragma unroll
      for (int r = 0; r < 4; r++) {
        const int m = m0 + wr * 32 + i * 16 + quad * 4 + r;
        out[(size_t)m * D_ + n] = acc[i][j][r] + bias;
      }
    }
  }
}

// ---------------------------------------------------------------------------
extern "C" void kernel_launch(void* const* d_in, const int* in_sizes, int n_in,
                              void* d_out, int out_size, void* d_ws, size_t ws_size,
                              hipStream_t stream) {
  const float* x  = (const float*)d_in[0];
  const float* Wq = (const float*)d_in[1];
  const float* Wk = (const float*)d_in[2];
  const float* Wv = (const float*)d_in[3];
  const float* Wo = (const float*)d_in[4];
  const float* bo = (const float*)d_in[5];
  float* out = (float*)d_out;

  // workspace carve (u16 elements): xb[4M] | wT[4M] | qkv[12M] | ctx[4M] = 48MB
  // then fp32 Opart partial buffer (38.3MB) for the chunked-attn path.
  // xb is dead after qkv_gemm -> reused as V^T buffer.
  u16* ws  = (u16*)d_ws;
  u16* xb  = ws;                                  // 4096*1024 (later: V^T)
  u16* wT  = xb + (size_t)M_ * D_;                // 4 * 1024*1024
  u16* qkv = wT + (size_t)4 * D_ * D_;            // 3 * 4096*1024
  u16* ctx = qkv + (size_t)3 * M_ * D_;           // 4096*1024
  u16* vT  = xb;
  float* Opart = (float*)(ctx + (size_t)M_ * D_); // at ws + 48MB

  cvt_x<<<dim3(M_ * D_ / (256 * 8)), 256, 0, stream>>>(x, xb);
  transpose_w<<<dim3(16, 16, 4), 256, 0, stream>>>(Wq, Wk, Wv, Wo, wT);
  qkv_gemm<<<dim3(D_ / 128, M_ / 128, 3), 256, 0, stream>>>(xb, wT, qkv);
  transpose_v<<<dim3(T_ / 64, B_ * H_), 256, 0, stream>>>(qkv + (size_t)2 * M_ * D_, vT);

  if (ws_size >= WS_BASE_BYTES + OPART_BYTES) {
    attn_chunk<<<dim3(40, B_ * H_), 256, 0, stream>>>(
        qkv, qkv + (size_t)M_ * D_, vT, ctx, Opart);
    attn_combine<<<dim3(12, B_ * H_), 256, 0, stream>>>(Opart, ctx);
  } else {
    attn_mono<<<dim3(T_ / 64, B_ * H_), 128, 0, stream>>>(
        qkv, qkv + (size_t)M_ * D_, vT, ctx);
  }

  out_gemm<<<dim3(D_ / 128, M_ / 64), 256, 0, stream>>>(ctx, wT + (size_t)3 * D_ * D_, bo, out);
}

// Round 5
// 195.918 us; speedup vs baseline: 1.4384x; 1.0135x over previous
//
#include <hip/hip_runtime.h>

// MultiHeadAttention fused: B=2, T=2048, D=1024, H=16, DH=64.
// Inputs fp32 (per reference), output fp32. Internally bf16 MFMA, fp32 accum.
// Pipeline: [cvt x] + [transpose W] -> [QKV gemm (m97 staging, Q pre-scaled)]
//           -> [transpose V] -> [flash attn, static-max, KV-CHUNKED]
//           -> [combine partials] -> [out gemm 64x128 + bias]
//
// R12: KV-chunk split for causal balance (attn 62->51us, occ 10->14%).
// R14 (REVERTED): direct-global K/V loads thrashed L2 (FETCH 64->197MB).
// R15 (REVERTED): 4-wave blocks — occupancy stuck at 15% either way, attn
//   51->56us. Residency is NOT the binding constraint.
// R16: prefetch-reorder. Old loop issued next-tile K/V loads BETWEEN the two
// barriers -> __syncthreads' vmcnt(0) drain at barrier2 exposed full L2/HBM
// latency on every kv-tile (serial per block; explains per-tile ~1800cyc).
// Moving the prefetch issue AFTER barrier2 lets the loads fly through the
// entire compute phase and drain at next iter's barrier1 instead.

typedef unsigned short u16;
typedef __attribute__((ext_vector_type(8))) short short8;   // 8 x bf16 (4 VGPRs)
typedef __attribute__((ext_vector_type(4))) short short4_t; // 4 x bf16 (8 B)
typedef __attribute__((ext_vector_type(4))) float f32x4;    // MFMA C/D frag

#define B_ 2
#define T_ 2048
#define D_ 1024
#define H_ 16
#define DH_ 64
#define M_ (B_ * T_)            // 4096 rows of x
#define SCALE_LOG2E 0.18033688011112042f  // (1/sqrt(64)) * log2(e) — folded into Q
#define NEG_BIG -3.0e4f         // mask sentinel: v_exp_f32(NEG_BIG) == 0

// partial-slot geometry: per (bh) 72 slots (qt 8..15: 2, 16..23: 3, 24..31: 4)
// slot payload: 64x64 fp32 O tile [q][dh] + 64 fp32 l  -> 4160 floats
#define SLOT_F 4160
#define SLOTS_PER_BH 72
#define OPART_BYTES ((size_t)32 * SLOTS_PER_BH * SLOT_F * 4)   // 38,338,560
#define WS_BASE_BYTES ((size_t)24 * 1024 * 1024 * 2)           // 48 MB (u16 pools)

// async global->LDS, 16B per lane; LDS dest = wave-uniform base + lane*16
#define GLOAD16(g, l)                                                     \
  __builtin_amdgcn_global_load_lds(                                       \
      (const __attribute__((address_space(1))) void*)(g),                 \
      (__attribute__((address_space(3))) void*)(l), 16, 0, 0)

__device__ __forceinline__ u16 f2bf(float f) {
  union { float f; unsigned u; } v; v.f = f;
  unsigned r = v.u + 0x7fffu + ((v.u >> 16) & 1u);  // RNE
  return (u16)(r >> 16);
}
__device__ __forceinline__ u16 f2bf_trunc(float f) {  // for P >= 0
  union { float f; unsigned u; } v; v.f = f;
  return (u16)(v.u >> 16);
}
__device__ __forceinline__ float exp2_raw(float x) {  // bare v_exp_f32
  float r;
  asm volatile("v_exp_f32 %0, %1" : "=v"(r) : "v"(x));
  return r;
}

// ---------------------------------------------------------------------------
// Kernel 0: convert x fp32 -> bf16. 4M elements, 8/thread.
// ---------------------------------------------------------------------------
__global__ __launch_bounds__(256) void cvt_x(const float* __restrict__ x,
                                             u16* __restrict__ xb) {
  const int i = (blockIdx.x * 256 + threadIdx.x) * 8;
  float4 a = *(const float4*)(x + i);
  float4 b = *(const float4*)(x + i + 4);
  short8 o;
  o[0] = (short)f2bf(a.x); o[1] = (short)f2bf(a.y);
  o[2] = (short)f2bf(a.z); o[3] = (short)f2bf(a.w);
  o[4] = (short)f2bf(b.x); o[5] = (short)f2bf(b.y);
  o[6] = (short)f2bf(b.z); o[7] = (short)f2bf(b.w);
  *(short8*)(xb + i) = o;
}

// ---------------------------------------------------------------------------
// Kernel 1: transpose + convert the 4 weight matrices fp32 [K][N] -> bf16 [N][K]
// grid (16,16,4), block 256. 64x64 tiles through LDS (+8 pad).
// ---------------------------------------------------------------------------
__global__ __launch_bounds__(256) void transpose_w(
    const float* __restrict__ w0, const float* __restrict__ w1,
    const float* __restrict__ w2, const float* __restrict__ w3,
    u16* __restrict__ outT) {
  __shared__ u16 Tl[64][72];
  const int z = blockIdx.z;
  const float* src = (z == 0) ? w0 : (z == 1) ? w1 : (z == 2) ? w2 : w3;
  const int r0 = blockIdx.y * 64, c0 = blockIdx.x * 64;
  const int tid = threadIdx.x;
  const int rr = tid >> 2, cc = (tid & 3) * 16;

  const float* p = src + (size_t)(r0 + rr) * D_ + c0 + cc;
  float4 f0 = *(const float4*)p;
  float4 f1 = *(const float4*)(p + 4);
  float4 f2 = *(const float4*)(p + 8);
  float4 f3 = *(const float4*)(p + 12);
  Tl[rr][cc + 0] = f2bf(f0.x); Tl[rr][cc + 1] = f2bf(f0.y);
  Tl[rr][cc + 2] = f2bf(f0.z); Tl[rr][cc + 3] = f2bf(f0.w);
  Tl[rr][cc + 4] = f2bf(f1.x); Tl[rr][cc + 5] = f2bf(f1.y);
  Tl[rr][cc + 6] = f2bf(f1.z); Tl[rr][cc + 7] = f2bf(f1.w);
  Tl[rr][cc + 8] = f2bf(f2.x); Tl[rr][cc + 9] = f2bf(f2.y);
  Tl[rr][cc +10] = f2bf(f2.z); Tl[rr][cc +11] = f2bf(f2.w);
  Tl[rr][cc +12] = f2bf(f3.x); Tl[rr][cc +13] = f2bf(f3.y);
  Tl[rr][cc +14] = f2bf(f3.z); Tl[rr][cc +15] = f2bf(f3.w);
  __syncthreads();

  u16* o = outT + (size_t)z * D_ * D_ + (size_t)(c0 + rr) * D_ + r0 + cc;
  short8 x0, x1;
#pragma unroll
  for (int i = 0; i < 8; i++) x0[i] = (short)Tl[cc + i][rr];
#pragma unroll
  for (int i = 0; i < 8; i++) x1[i] = (short)Tl[cc + 8 + i][rr];
  *(short8*)o = x0;
  *(short8*)(o + 8) = x1;
}

// ---------------------------------------------------------------------------
// Kernel 2: QKV projection. C[m][n] = sum_k x[m][k] * WT[n][k]. (bf16 in/out)
// m97-style staging. Q (z==0) is pre-scaled by SCALE_LOG2E.
// grid (8, 32, 3), block 256.
// ---------------------------------------------------------------------------
__global__ __launch_bounds__(256) void qkv_gemm(
    const u16* __restrict__ x, const u16* __restrict__ wT,
    u16* __restrict__ qkv) {
  __shared__ u16 As[128][32];  // unpadded: global_load_lds needs lane-order layout
  __shared__ u16 Bs[128][32];

  const int z = blockIdx.z;
  const u16* W = wT + (size_t)z * D_ * D_;
  u16* out = qkv + (size_t)z * M_ * D_;
  const int n0 = blockIdx.x * 128;
  const int m0 = blockIdx.y * 128;
  const int tid = threadIdx.x;
  const int lane = tid & 63, w = tid >> 6;
  const int quad = lane >> 4, l16 = lane & 15;
  const int wr = w >> 1, wc = w & 1;

  f32x4 acc[4][4] = {};
  const int grow = w * 16 + (lane >> 2);
  const int gcol = (lane & 3) * 8;
  u16* lA = (u16*)As + w * 512;   // 1024 B per wave
  u16* lB = (u16*)Bs + w * 512;

  for (int k0 = 0; k0 < D_; k0 += 32) {
    const u16* gA = x + (size_t)(m0 + grow) * D_ + k0 + gcol;
    const u16* gB = W + (size_t)(n0 + grow) * D_ + k0 + gcol;
    GLOAD16(gA, lA);
    GLOAD16(gA + (size_t)64 * D_, lA + 2048);
    GLOAD16(gB, lB);
    GLOAD16(gB + (size_t)64 * D_, lB + 2048);
    __syncthreads();

    short8 af[4], bf[4];
#pragma unroll
    for (int i = 0; i < 4; i++)
      af[i] = *(const short8*)&As[wr * 64 + i * 16 + l16][quad * 8];
#pragma unroll
    for (int i = 0; i < 4; i++)
      bf[i] = *(const short8*)&Bs[wc * 64 + i * 16 + l16][quad * 8];
#pragma unroll
    for (int i = 0; i < 4; i++)
#pragma unroll
      for (int j = 0; j < 4; j++)
        acc[i][j] = __builtin_amdgcn_mfma_f32_16x16x32_bf16(af[i], bf[j], acc[i][j], 0, 0, 0);
    __syncthreads();
  }

  const float osc = (z == 0) ? SCALE_LOG2E : 1.0f;  // pre-scale Q only
#pragma unroll
  for (int i = 0; i < 4; i++) {
#pragma unroll
    for (int j = 0; j < 4; j++) {
      const int n = n0 + wc * 64 + j * 16 + l16;
      const int h = n >> 6, dh = n & 63;
#pragma unroll
      for (int r = 0; r < 4; r++) {
        const int m = m0 + wr * 64 + i * 16 + quad * 4 + r;
        const int b = m >> 11, t = m & (T_ - 1);
        out[(((size_t)(b * H_ + h)) * T_ + t) * DH_ + dh] = f2bf(acc[i][j][r] * osc);
      }
    }
  }
}

// ---------------------------------------------------------------------------
// Kernel 2b: transpose V [bh][t][dh] -> V^T [bh][dh][t]. grid (32, 32), block 256.
// ---------------------------------------------------------------------------
__global__ __launch_bounds__(256) void transpose_v(
    const u16* __restrict__ v, u16* __restrict__ vT) {
  __shared__ u16 Tl[64][72];
  const int t0 = blockIdx.x * 64;
  const int bh = blockIdx.y;
  const int tid = threadIdx.x;
  const int rr = tid >> 2, cc = (tid & 3) * 16;

  const u16* p = v + (size_t)bh * T_ * DH_ + (size_t)(t0 + rr) * DH_ + cc;
  short8 a0 = *(const short8*)p;
  short8 a1 = *(const short8*)(p + 8);
  *(short8*)&Tl[rr][cc] = a0;
  *(short8*)&Tl[rr][cc + 8] = a1;
  __syncthreads();

  u16* o = vT + (size_t)bh * DH_ * T_ + (size_t)rr * T_ + t0 + cc;
  short8 x0, x1;
#pragma unroll
  for (int i = 0; i < 8; i++) x0[i] = (short)Tl[cc + i][rr];
#pragma unroll
  for (int i = 0; i < 8; i++) x1[i] = (short)Tl[cc + 8 + i][rr];
  *(short8*)o = x0;
  *(short8*)(o + 8) = x1;
}

// ---------------------------------------------------------------------------
// shared helper: slot base within a bh for split q-tile qt (qt in 8..31)
// ---------------------------------------------------------------------------
__device__ __forceinline__ int slot_base(int qt) {
  return (qt < 16) ? (qt - 8) * 2
       : (qt < 24) ? 16 + (qt - 16) * 3
                   : 40 + (qt - 24) * 4;
}

// ---------------------------------------------------------------------------
// Kernel 3: causal flash attention, static-max softmax, KV-CHUNKED.
// grid (80, 32), block 128 (2 waves x 32 q-rows). Chunk cid covers q-tile qt
// with nc = 1+qt/8 chunks of <=8 kv tiles. nc==1 -> direct bf16 ctx write;
// nc>1 -> fp32 partial (O [q][dh] + l) plain stores, combined by kernel 3b.
// R16: next-tile prefetch issued AFTER the compute-ready barrier so the
// loads stay in flight through QK^T/exp/PV and drain at next barrier1.
// ---------------------------------------------------------------------------
__global__ __launch_bounds__(128) void attn_chunk(
    const u16* __restrict__ qg, const u16* __restrict__ kg,
    const u16* __restrict__ vtg, u16* __restrict__ ctx,
    float* __restrict__ Opart) {
  __shared__ u16 Ks[64][72];        // [kv][dh], +8 pad
  __shared__ u16 Vs[64][72];        // [dh][kv], +8 pad (from vT global)
  __shared__ u16 Ps[2][2][16][72];  // [wave][qfrag][q][kv 0..63 + pad]

  const int cid = 79 - blockIdx.x;  // big chunks (high qt) dispatch first
  int qt, c, nc;
  if (cid < 8)       { qt = cid;                    c = 0;               nc = 1; }
  else if (cid < 24) { qt = 8  + ((cid - 8) >> 1);  c = (cid - 8) & 1;   nc = 2; }
  else if (cid < 48) { qt = 16 + (cid - 24) / 3;    c = (cid - 24) % 3;  nc = 3; }
  else               { qt = 24 + ((cid - 48) >> 2); c = (cid - 48) & 3;  nc = 4; }
  const int nt = qt + 1;
  const int kv_lo = (c * nt / nc) * 64;
  const int kv_hi = ((c + 1) * nt / nc) * 64;   // exclusive
  const int q0 = qt * 64;

  const int bh = blockIdx.y;
  const int tid = threadIdx.x;
  const int w = tid >> 6, lane = tid & 63;
  const int quad = lane >> 4, l16 = lane & 15;
  const size_t baseQK = (size_t)bh * T_ * DH_;
  const size_t baseV  = (size_t)bh * DH_ * T_;

  // wave w owns q rows [q0+32w, q0+32w+32) as two 16-row fragments
  const int qrowA = q0 + w * 32 + l16;
  const int qrowB = qrowA + 16;
  short8 qfA0 = *(const short8*)(qg + baseQK + (size_t)qrowA * DH_ + quad * 8);
  short8 qfA1 = *(const short8*)(qg + baseQK + (size_t)qrowA * DH_ + 32 + quad * 8);
  short8 qfB0 = *(const short8*)(qg + baseQK + (size_t)qrowB * DH_ + quad * 8);
  short8 qfB1 = *(const short8*)(qg + baseQK + (size_t)qrowB * DH_ + 32 + quad * 8);

  f32x4 oaccA[4] = {}, oaccB[4] = {};  // O^T: row dh = cb*16+quad*4+r, col q = l16
  float liA = 0.f, liB = 0.f;          // per-lane partial sum (16 kv slots/iter)

  const int srow = tid >> 1;          // 0..63
  const int scol = (tid & 1) * 32;    // 0 or 32 (64 B per thread per matrix)

  // prefetch first tile of this chunk into registers
  const u16* kp = kg + baseQK + (size_t)(kv_lo + srow) * DH_ + scol;
  const u16* vp = vtg + baseV + (size_t)srow * T_ + kv_lo + scol;
  short8 kr0 = *(const short8*)kp;
  short8 kr1 = *(const short8*)(kp + 8);
  short8 kr2 = *(const short8*)(kp + 16);
  short8 kr3 = *(const short8*)(kp + 24);
  short8 vr0 = *(const short8*)vp;
  short8 vr1 = *(const short8*)(vp + 8);
  short8 vr2 = *(const short8*)(vp + 16);
  short8 vr3 = *(const short8*)(vp + 24);

  for (int kv0 = kv_lo; kv0 < kv_hi; kv0 += 64) {
    __syncthreads();                 // barrier1: LDS free; drains in-flight prefetch
    *(short8*)&Ks[srow][scol]      = kr0;
    *(short8*)&Ks[srow][scol + 8]  = kr1;
    *(short8*)&Ks[srow][scol + 16] = kr2;
    *(short8*)&Ks[srow][scol + 24] = kr3;
    *(short8*)&Vs[srow][scol]      = vr0;
    *(short8*)&Vs[srow][scol + 8]  = vr1;
    *(short8*)&Vs[srow][scol + 16] = vr2;
    *(short8*)&Vs[srow][scol + 24] = vr3;
    __syncthreads();                 // barrier2: LDS ready (lgkm drain only)

    // R16: issue next tile's loads NOW — they fly under the whole compute
    // phase and are only drained at next iteration's barrier1.
    if (kv0 + 64 < kv_hi) {
      const u16* kn = kg + baseQK + (size_t)(kv0 + 64 + srow) * DH_ + scol;
      const u16* vn = vtg + baseV + (size_t)srow * T_ + kv0 + 64 + scol;
      kr0 = *(const short8*)kn;
      kr1 = *(const short8*)(kn + 8);
      kr2 = *(const short8*)(kn + 16);
      kr3 = *(const short8*)(kn + 24);
      vr0 = *(const short8*)vn;
      vr1 = *(const short8*)(vn + 8);
      vr2 = *(const short8*)(vn + 16);
      vr3 = *(const short8*)(vn + 24);
    }

    // K fragments read ONCE, shared by both q-fragments
    short8 kf0[4], kf1[4];
#pragma unroll
    for (int cb = 0; cb < 4; cb++) {
      kf0[cb] = *(const short8*)&Ks[cb * 16 + l16][quad * 8];
      kf1[cb] = *(const short8*)&Ks[cb * 16 + l16][32 + quad * 8];
    }

    // S^T = K·Q^T for both fragments (Q pre-scaled by SCALE_LOG2E)
    f32x4 svA[4], svB[4];
    __builtin_amdgcn_s_setprio(1);
#pragma unroll
    for (int cb = 0; cb < 4; cb++) {
      f32x4 z = {};
      svA[cb] = __builtin_amdgcn_mfma_f32_16x16x32_bf16(kf0[cb], qfA0, z, 0, 0, 0);
      svA[cb] = __builtin_amdgcn_mfma_f32_16x16x32_bf16(kf1[cb], qfA1, svA[cb], 0, 0, 0);
      svB[cb] = __builtin_amdgcn_mfma_f32_16x16x32_bf16(kf0[cb], qfB0, z, 0, 0, 0);
      svB[cb] = __builtin_amdgcn_mfma_f32_16x16x32_bf16(kf1[cb], qfB1, svB[cb], 0, 0, 0);
    }
    __builtin_amdgcn_s_setprio(0);

    // p = exp2(s) (static max = 0); mask only the diagonal tile
    float pA[4][4], pB[4][4];
    if (kv0 == q0) {
#pragma unroll
      for (int cb = 0; cb < 4; cb++)
#pragma unroll
        for (int r = 0; r < 4; r++) {
          const int kv = kv0 + cb * 16 + quad * 4 + r;
          pA[cb][r] = exp2_raw((kv <= qrowA) ? svA[cb][r] : NEG_BIG);
          pB[cb][r] = exp2_raw((kv <= qrowB) ? svB[cb][r] : NEG_BIG);
        }
    } else {
#pragma unroll
      for (int cb = 0; cb < 4; cb++)
#pragma unroll
        for (int r = 0; r < 4; r++) {
          pA[cb][r] = exp2_raw(svA[cb][r]);
          pB[cb][r] = exp2_raw(svB[cb][r]);
        }
    }
#pragma unroll
    for (int cb = 0; cb < 4; cb++)
#pragma unroll
      for (int r = 0; r < 4; r++) { liA += pA[cb][r]; liB += pB[cb][r]; }

    // V fragments read ONCE, shared by both q-fragments
    short8 vf0[4], vf1[4];
#pragma unroll
    for (int cb = 0; cb < 4; cb++) {
      vf0[cb] = *(const short8*)&Vs[cb * 16 + l16][quad * 8];
      vf1[cb] = *(const short8*)&Vs[cb * 16 + l16][32 + quad * 8];
    }

    // P round-trip (packed b64 writes; wave-private LDS is in-order) + PV
#pragma unroll
    for (int cb = 0; cb < 4; cb++) {
      short4_t pkA, pkB;
#pragma unroll
      for (int r = 0; r < 4; r++) {
        pkA[r] = (short)f2bf_trunc(pA[cb][r]);
        pkB[r] = (short)f2bf_trunc(pB[cb][r]);
      }
      *(short4_t*)&Ps[w][0][l16][cb * 16 + quad * 4] = pkA;
      *(short4_t*)&Ps[w][1][l16][cb * 16 + quad * 4] = pkB;
    }
    short8 paA0 = *(const short8*)&Ps[w][0][l16][quad * 8];
    short8 paA1 = *(const short8*)&Ps[w][0][l16][32 + quad * 8];
    short8 paB0 = *(const short8*)&Ps[w][1][l16][quad * 8];
    short8 paB1 = *(const short8*)&Ps[w][1][l16][32 + quad * 8];
    __builtin_amdgcn_s_setprio(1);
#pragma unroll
    for (int cb = 0; cb < 4; cb++) {
      oaccA[cb] = __builtin_amdgcn_mfma_f32_16x16x32_bf16(vf0[cb], paA0, oaccA[cb], 0, 0, 0);
      oaccA[cb] = __builtin_amdgcn_mfma_f32_16x16x32_bf16(vf1[cb], paA1, oaccA[cb], 0, 0, 0);
      oaccB[cb] = __builtin_amdgcn_mfma_f32_16x16x32_bf16(vf0[cb], paB0, oaccB[cb], 0, 0, 0);
      oaccB[cb] = __builtin_amdgcn_mfma_f32_16x16x32_bf16(vf1[cb], paB1, oaccB[cb], 0, 0, 0);
    }
    __builtin_amdgcn_s_setprio(0);
  }

  // reduce l across quads (all lanes end with the full row sum)
  liA += __shfl_xor(liA, 16, 64); liA += __shfl_xor(liA, 32, 64);
  liB += __shfl_xor(liB, 16, 64); liB += __shfl_xor(liB, 32, 64);

  if (nc == 1) {
    // sole chunk: normalize and write ctx bf16 directly
    const int b = bh >> 4, h = bh & 15;
    const float invA = 1.0f / liA, invB = 1.0f / liB;
    u16* outA = ctx + ((size_t)(b * T_ + qrowA)) * D_ + h * 64 + quad * 4;
    u16* outB = ctx + ((size_t)(b * T_ + qrowB)) * D_ + h * 64 + quad * 4;
#pragma unroll
    for (int cb = 0; cb < 4; cb++) {
      short4_t oA, oB;
#pragma unroll
      for (int r = 0; r < 4; r++) {
        oA[r] = (short)f2bf(oaccA[cb][r] * invA);
        oB[r] = (short)f2bf(oaccB[cb][r] * invB);
      }
      *(short4_t*)(outA + cb * 16) = oA;
      *(short4_t*)(outB + cb * 16) = oB;
    }
  } else {
    // partial store: O tile [q 64][dh 64] fp32 (+ l[64]) -> float4 per cb
    float* slot = Opart + ((size_t)bh * SLOTS_PER_BH + slot_base(qt) + c) * SLOT_F;
    float* pA = slot + (size_t)(w * 32 + l16) * 64 + quad * 4;
    float* pB = slot + (size_t)(w * 32 + 16 + l16) * 64 + quad * 4;
#pragma unroll
    for (int cb = 0; cb < 4; cb++) {
      *(f32x4*)(pA + cb * 16) = oaccA[cb];
      *(f32x4*)(pB + cb * 16) = oaccB[cb];
    }
    if (quad == 0) {
      slot[4096 + w * 32 + l16] = liA;
      slot[4096 + w * 32 + 16 + l16] = liB;
    }
  }
}

// ---------------------------------------------------------------------------
// Kernel 3b: combine partials for qt >= 8. grid (24, 32), block 256.
// Each block: one (bh, qt) 64x64 tile; sums nc<=4 slots, normalizes, bf16 out.
// ---------------------------------------------------------------------------
__global__ __launch_bounds__(256) void attn_combine(
    const float* __restrict__ Opart, u16* __restrict__ ctx) {
  __shared__ float ls[64];
  const int qt = blockIdx.x + 8;
  const int bh = blockIdx.y;
  const int nc = 1 + (qt >> 3);     // 2, 3 or 4
  const float* slot0 = Opart + ((size_t)bh * SLOTS_PER_BH + slot_base(qt)) * SLOT_F;
  const int tid = threadIdx.x;

  if (tid < 64) {
    float s = 0.f;
    for (int c = 0; c < nc; c++) s += slot0[(size_t)c * SLOT_F + 4096 + tid];
    ls[tid] = 1.0f / s;
  }
  __syncthreads();

  const int q = tid >> 2, d0 = (tid & 3) * 16;
  const float* p = slot0 + (size_t)q * 64 + d0;
  f32x4 a0 = *(const f32x4*)(p);
  f32x4 a1 = *(const f32x4*)(p + 4);
  f32x4 a2 = *(const f32x4*)(p + 8);
  f32x4 a3 = *(const f32x4*)(p + 12);
  for (int c = 1; c < nc; c++) {
    const float* pc = p + (size_t)c * SLOT_F;
    a0 += *(const f32x4*)(pc);
    a1 += *(const f32x4*)(pc + 4);
    a2 += *(const f32x4*)(pc + 8);
    a3 += *(const f32x4*)(pc + 12);
  }
  const float inv = ls[q];
  short8 o0, o1;
#pragma unroll
  for (int i = 0; i < 4; i++) {
    o0[i]     = (short)f2bf(a0[i] * inv);
    o0[i + 4] = (short)f2bf(a1[i] * inv);
    o1[i]     = (short)f2bf(a2[i] * inv);
    o1[i + 4] = (short)f2bf(a3[i] * inv);
  }
  const int b = bh >> 4, h = bh & 15;
  u16* op = ctx + ((size_t)(b * T_ + qt * 64 + q)) * D_ + h * 64 + d0;
  *(short8*)op = o0;
  *(short8*)(op + 8) = o1;
}

// ---------------------------------------------------------------------------
// Kernel 3-mono: fallback (previous measured-best attn) if ws too small.
// ---------------------------------------------------------------------------
__global__ __launch_bounds__(128) void attn_mono(
    const u16* __restrict__ qg, const u16* __restrict__ kg,
    const u16* __restrict__ vtg, u16* __restrict__ ctx) {
  __shared__ u16 Ks[64][72];
  __shared__ u16 Vs[64][72];
  __shared__ u16 Ps[2][2][16][72];

  const int qt = gridDim.x - 1 - blockIdx.x;
  const int bh = blockIdx.y;
  const int tid = threadIdx.x;
  const int w = tid >> 6, lane = tid & 63;
  const int quad = lane >> 4, l16 = lane & 15;
  const int q0 = qt * 64;
  const size_t baseQK = (size_t)bh * T_ * DH_;
  const size_t baseV  = (size_t)bh * DH_ * T_;

  const int qrowA = q0 + w * 32 + l16;
  const int qrowB = qrowA + 16;
  short8 qfA0 = *(const short8*)(qg + baseQK + (size_t)qrowA * DH_ + quad * 8);
  short8 qfA1 = *(const short8*)(qg + baseQK + (size_t)qrowA * DH_ + 32 + quad * 8);
  short8 qfB0 = *(const short8*)(qg + baseQK + (size_t)qrowB * DH_ + quad * 8);
  short8 qfB1 = *(const short8*)(qg + baseQK + (size_t)qrowB * DH_ + 32 + quad * 8);

  f32x4 oaccA[4] = {}, oaccB[4] = {};
  float liA = 0.f, liB = 0.f;

  const int srow = tid >> 1;
  const int scol = (tid & 1) * 32;

  const u16* kp = kg + baseQK + (size_t)srow * DH_ + scol;
  const u16* vp = vtg + baseV + (size_t)srow * T_ + scol;
  short8 kr0 = *(const short8*)kp;
  short8 kr1 = *(const short8*)(kp + 8);
  short8 kr2 = *(const short8*)(kp + 16);
  short8 kr3 = *(const short8*)(kp + 24);
  short8 vr0 = *(const short8*)vp;
  short8 vr1 = *(const short8*)(vp + 8);
  short8 vr2 = *(const short8*)(vp + 16);
  short8 vr3 = *(const short8*)(vp + 24);

  for (int kv0 = 0; kv0 <= q0; kv0 += 64) {
    __syncthreads();
    *(short8*)&Ks[srow][scol]      = kr0;
    *(short8*)&Ks[srow][scol + 8]  = kr1;
    *(short8*)&Ks[srow][scol + 16] = kr2;
    *(short8*)&Ks[srow][scol + 24] = kr3;
    *(short8*)&Vs[srow][scol]      = vr0;
    *(short8*)&Vs[srow][scol + 8]  = vr1;
    *(short8*)&Vs[srow][scol + 16] = vr2;
    *(short8*)&Vs[srow][scol + 24] = vr3;
    __syncthreads();
    if (kv0 < q0) {
      const u16* kn = kg + baseQK + (size_t)(kv0 + 64 + srow) * DH_ + scol;
      const u16* vn = vtg + baseV + (size_t)srow * T_ + kv0 + 64 + scol;
      kr0 = *(const short8*)kn;
      kr1 = *(const short8*)(kn + 8);
      kr2 = *(const short8*)(kn + 16);
      kr3 = *(const short8*)(kn + 24);
      vr0 = *(const short8*)vn;
      vr1 = *(const short8*)(vn + 8);
      vr2 = *(const short8*)(vn + 16);
      vr3 = *(const short8*)(vn + 24);
    }

    short8 kf0[4], kf1[4];
#pragma unroll
    for (int cb = 0; cb < 4; cb++) {
      kf0[cb] = *(const short8*)&Ks[cb * 16 + l16][quad * 8];
      kf1[cb] = *(const short8*)&Ks[cb * 16 + l16][32 + quad * 8];
    }

    f32x4 svA[4], svB[4];
#pragma unroll
    for (int cb = 0; cb < 4; cb++) {
      f32x4 z = {};
      svA[cb] = __builtin_amdgcn_mfma_f32_16x16x32_bf16(kf0[cb], qfA0, z, 0, 0, 0);
      svA[cb] = __builtin_amdgcn_mfma_f32_16x16x32_bf16(kf1[cb], qfA1, svA[cb], 0, 0, 0);
      svB[cb] = __builtin_amdgcn_mfma_f32_16x16x32_bf16(kf0[cb], qfB0, z, 0, 0, 0);
      svB[cb] = __builtin_amdgcn_mfma_f32_16x16x32_bf16(kf1[cb], qfB1, svB[cb], 0, 0, 0);
    }

    float pA[4][4], pB[4][4];
    if (kv0 == q0) {
#pragma unroll
      for (int cb = 0; cb < 4; cb++)
#pragma unroll
        for (int r = 0; r < 4; r++) {
          const int kv = kv0 + cb * 16 + quad * 4 + r;
          pA[cb][r] = exp2_raw((kv <= qrowA) ? svA[cb][r] : NEG_BIG);
          pB[cb][r] = exp2_raw((kv <= qrowB) ? svB[cb][r] : NEG_BIG);
        }
    } else {
#pragma unroll
      for (int cb = 0; cb < 4; cb++)
#pragma unroll
        for (int r = 0; r < 4; r++) {
          pA[cb][r] = exp2_raw(svA[cb][r]);
          pB[cb][r] = exp2_raw(svB[cb][r]);
        }
    }
#pragma unroll
    for (int cb = 0; cb < 4; cb++)
#pragma unroll
      for (int r = 0; r < 4; r++) { liA += pA[cb][r]; liB += pB[cb][r]; }

    short8 vf0[4], vf1[4];
#pragma unroll
    for (int cb = 0; cb < 4; cb++) {
      vf0[cb] = *(const short8*)&Vs[cb * 16 + l16][quad * 8];
      vf1[cb] = *(const short8*)&Vs[cb * 16 + l16][32 + quad * 8];
    }

#pragma unroll
    for (int cb = 0; cb < 4; cb++) {
      short4_t pkA, pkB;
#pragma unroll
      for (int r = 0; r < 4; r++) {
        pkA[r] = (short)f2bf_trunc(pA[cb][r]);
        pkB[r] = (short)f2bf_trunc(pB[cb][r]);
      }
      *(short4_t*)&Ps[w][0][l16][cb * 16 + quad * 4] = pkA;
      *(short4_t*)&Ps[w][1][l16][cb * 16 + quad * 4] = pkB;
    }
    short8 paA0 = *(const short8*)&Ps[w][0][l16][quad * 8];
    short8 paA1 = *(const short8*)&Ps[w][0][l16][32 + quad * 8];
    short8 paB0 = *(const short8*)&Ps[w][1][l16][quad * 8];
    short8 paB1 = *(const short8*)&Ps[w][1][l16][32 + quad * 8];
#pragma unroll
    for (int cb = 0; cb < 4; cb++) {
      oaccA[cb] = __builtin_amdgcn_mfma_f32_16x16x32_bf16(vf0[cb], paA0, oaccA[cb], 0, 0, 0);
      oaccA[cb] = __builtin_amdgcn_mfma_f32_16x16x32_bf16(vf1[cb], paA1, oaccA[cb], 0, 0, 0);
      oaccB[cb] = __builtin_amdgcn_mfma_f32_16x16x32_bf16(vf0[cb], paB0, oaccB[cb], 0, 0, 0);
      oaccB[cb] = __builtin_amdgcn_mfma_f32_16x16x32_bf16(vf1[cb], paB1, oaccB[cb], 0, 0, 0);
    }
  }

  liA += __shfl_xor(liA, 16, 64); liA += __shfl_xor(liA, 32, 64);
  liB += __shfl_xor(liB, 16, 64); liB += __shfl_xor(liB, 32, 64);
  const int b = bh >> 4, h = bh & 15;
  const float invA = 1.0f / liA, invB = 1.0f / liB;
  u16* outA = ctx + ((size_t)(b * T_ + qrowA)) * D_ + h * 64 + quad * 4;
  u16* outB = ctx + ((size_t)(b * T_ + qrowB)) * D_ + h * 64 + quad * 4;
#pragma unroll
  for (int cb = 0; cb < 4; cb++) {
    short4_t oA, oB;
#pragma unroll
    for (int r = 0; r < 4; r++) {
      oA[r] = (short)f2bf(oaccA[cb][r] * invA);
      oB[r] = (short)f2bf(oaccB[cb][r] * invB);
    }
    *(short4_t*)(outA + cb * 16) = oA;
    *(short4_t*)(outB + cb * 16) = oB;
  }
}

// ---------------------------------------------------------------------------
// Kernel 4: output projection + bias (m97 staging). out = ctx @ WoT^T + bo.
// 64x128 tile -> grid (8, 64) = 512 blocks = 2/CU (kept from R11: helped).
// block 256, 4 waves 2x2; each wave 32m x 64n (acc[2][4]). fp32 output.
// ---------------------------------------------------------------------------
__global__ __launch_bounds__(256) void out_gemm(
    const u16* __restrict__ ctx, const u16* __restrict__ woT,
    const float* __restrict__ bo, float* __restrict__ out) {
  __shared__ u16 As[64][32];
  __shared__ u16 Bs[128][32];

  const int n0 = blockIdx.x * 128;
  const int m0 = blockIdx.y * 64;
  const int tid = threadIdx.x;
  const int lane = tid & 63, w = tid >> 6;
  const int quad = lane >> 4, l16 = lane & 15;
  const int wr = w >> 1, wc = w & 1;

  f32x4 acc[2][4] = {};
  const int grow = w * 16 + (lane >> 2);
  const int gcol = (lane & 3) * 8;
  u16* lA = (u16*)As + w * 512;   // 1024 B per wave (A: 64 rows, 1 inst)
  u16* lB = (u16*)Bs + w * 512;

  for (int k0 = 0; k0 < D_; k0 += 32) {
    const u16* gA = ctx + (size_t)(m0 + grow) * D_ + k0 + gcol;
    const u16* gB = woT + (size_t)(n0 + grow) * D_ + k0 + gcol;
    GLOAD16(gA, lA);
    GLOAD16(gB, lB);
    GLOAD16(gB + (size_t)64 * D_, lB + 2048);
    __syncthreads();

    short8 af[2], bf[4];
#pragma unroll
    for (int i = 0; i < 2; i++)
      af[i] = *(const short8*)&As[wr * 32 + i * 16 + l16][quad * 8];
#pragma unroll
    for (int i = 0; i < 4; i++)
      bf[i] = *(const short8*)&Bs[wc * 64 + i * 16 + l16][quad * 8];
#pragma unroll
    for (int i = 0; i < 2; i++)
#pragma unroll
      for (int j = 0; j < 4; j++)
        acc[i][j] = __builtin_amdgcn_mfma_f32_16x16x32_bf16(af[i], bf[j], acc[i][j], 0, 0, 0);
    __syncthreads();
  }

#pragma unroll
  for (int i = 0; i < 2; i++) {
#pragma unroll
    for (int j = 0; j < 4; j++) {
      const int n = n0 + wc * 64 + j * 16 + l16;
      const float bias = bo[n];
#pragma unroll
      for (int r = 0; r < 4; r++) {
        const int m = m0 + wr * 32 + i * 16 + quad * 4 + r;
        out[(size_t)m * D_ + n] = acc[i][j][r] + bias;
      }
    }
  }
}

// ---------------------------------------------------------------------------
extern "C" void kernel_launch(void* const* d_in, const int* in_sizes, int n_in,
                              void* d_out, int out_size, void* d_ws, size_t ws_size,
                              hipStream_t stream) {
  const float* x  = (const float*)d_in[0];
  const float* Wq = (const float*)d_in[1];
  const float* Wk = (const float*)d_in[2];
  const float* Wv = (const float*)d_in[3];
  const float* Wo = (const float*)d_in[4];
  const float* bo = (const float*)d_in[5];
  float* out = (float*)d_out;

  // workspace carve (u16 elements): xb[4M] | wT[4M] | qkv[12M] | ctx[4M] = 48MB
  // then fp32 Opart partial buffer (38.3MB) for the chunked-attn path.
  // xb is dead after qkv_gemm -> reused as V^T buffer.
  u16* ws  = (u16*)d_ws;
  u16* xb  = ws;                                  // 4096*1024 (later: V^T)
  u16* wT  = xb + (size_t)M_ * D_;                // 4 * 1024*1024
  u16* qkv = wT + (size_t)4 * D_ * D_;            // 3 * 4096*1024
  u16* ctx = qkv + (size_t)3 * M_ * D_;           // 4096*1024
  u16* vT  = xb;
  float* Opart = (float*)(ctx + (size_t)M_ * D_); // at ws + 48MB

  cvt_x<<<dim3(M_ * D_ / (256 * 8)), 256, 0, stream>>>(x, xb);
  transpose_w<<<dim3(16, 16, 4), 256, 0, stream>>>(Wq, Wk, Wv, Wo, wT);
  qkv_gemm<<<dim3(D_ / 128, M_ / 128, 3), 256, 0, stream>>>(xb, wT, qkv);
  transpose_v<<<dim3(T_ / 64, B_ * H_), 256, 0, stream>>>(qkv + (size_t)2 * M_ * D_, vT);

  if (ws_size >= WS_BASE_BYTES + OPART_BYTES) {
    attn_chunk<<<dim3(80, B_ * H_), 128, 0, stream>>>(
        qkv, qkv + (size_t)M_ * D_, vT, ctx, Opart);
    attn_combine<<<dim3(24, B_ * H_), 256, 0, stream>>>(Opart, ctx);
  } else {
    attn_mono<<<dim3(T_ / 64, B_ * H_), 128, 0, stream>>>(
        qkv, qkv + (size_t)M_ * D_, vT, ctx);
  }

  out_gemm<<<dim3(D_ / 128, M_ / 64), 256, 0, stream>>>(ctx, wT + (size_t)3 * D_ * D_, bo, out);
}